// Round 6
// baseline (3961.360 us; speedup 1.0000x reference)
//
#include <hip/hip_runtime.h>
#include <math.h>

namespace {

constexpr int B = 4, N = 128, FIN = 16, F = 64, H = 4, K = 50, C = 256;
constexpr int BN = B * N;
constexpr float EPS = 1e-5f;

__device__ __forceinline__ float silu_f(float x) { return x / (1.0f + __expf(-x)); }
__device__ __forceinline__ float tanh_f(float x) { return 1.0f - 2.0f / (__expf(2.0f * x) + 1.0f); }

__global__ void k_init(const float* __restrict__ x, const float* __restrict__ v,
                       float* __restrict__ xw, float* __restrict__ vw, float* __restrict__ sld) {
  int t = blockIdx.x * blockDim.x + threadIdx.x;
  if (t < B * N * 3) { xw[t] = x[t]; vw[t] = v[t]; }
  if (t < B) sld[t] = 0.0f;
}

__global__ __launch_bounds__(F) void k_embed(const float* __restrict__ hin,
    const float* __restrict__ w1, const float* __restrict__ b1,
    const float* __restrict__ w2, const float* __restrict__ b2, float* __restrict__ h0) {
  int node = blockIdx.x, f = threadIdx.x;
  __shared__ float t1[F];
  float acc = b1[f];
  #pragma unroll
  for (int r = 0; r < FIN; ++r) acc += hin[node * FIN + r] * w1[r * F + f];
  t1[f] = silu_f(acc);
  __syncthreads();
  float a0 = b2[f], a1 = 0.f, a2 = 0.f, a3 = 0.f;
  #pragma unroll
  for (int r = 0; r < F; r += 4) {
    a0 += t1[r] * w2[r * F + f];
    a1 += t1[r + 1] * w2[(r + 1) * F + f];
    a2 += t1[r + 2] * w2[(r + 2) * F + f];
    a3 += t1[r + 3] * w2[(r + 3) * F + f];
  }
  h0[node * F + f] = (a0 + a1) + (a2 + a3);
}

// Per-node precomputation at flow start: hkA/hkB (edge_in halves), e1A/e1B (eo1 halves).
__global__ __launch_bounds__(256) void k_pre(const float* __restrict__ h0, float* __restrict__ hw,
    const float* __restrict__ ein_w, const float* __restrict__ eo1w,
    float* __restrict__ hkA, float* __restrict__ hkB,
    float* __restrict__ e1A, float* __restrict__ e1B) {
  int node = blockIdx.x, t = threadIdx.x;
  __shared__ float s_h[F];
  if (t < F) s_h[t] = h0[node * F + t];
  __syncthreads();
  if (t < F) hw[node * F + t] = s_h[t];
  if (t < 228) {
    float a0 = 0.f, a1 = 0.f, a2 = 0.f, a3 = 0.f;
    if (t < 50) { int k = t;
      #pragma unroll
      for (int r = 0; r < F; r += 4) {
        a0 += s_h[r] * ein_w[r * K + k];       a1 += s_h[r + 1] * ein_w[(r + 1) * K + k];
        a2 += s_h[r + 2] * ein_w[(r + 2) * K + k]; a3 += s_h[r + 3] * ein_w[(r + 3) * K + k];
      }
      hkA[node * K + k] = (a0 + a1) + (a2 + a3);
    } else if (t < 100) { int k = t - 50;
      #pragma unroll
      for (int r = 0; r < F; r += 4) {
        a0 += s_h[r] * ein_w[(F + r) * K + k];       a1 += s_h[r + 1] * ein_w[(F + r + 1) * K + k];
        a2 += s_h[r + 2] * ein_w[(F + r + 2) * K + k]; a3 += s_h[r + 3] * ein_w[(F + r + 3) * K + k];
      }
      hkB[node * K + k] = (a0 + a1) + (a2 + a3);
    } else if (t < 164) { int c = t - 100;
      #pragma unroll
      for (int r = 0; r < F; r += 4) {
        a0 += s_h[r] * eo1w[r * F + c];       a1 += s_h[r + 1] * eo1w[(r + 1) * F + c];
        a2 += s_h[r + 2] * eo1w[(r + 2) * F + c]; a3 += s_h[r + 3] * eo1w[(r + 3) * F + c];
      }
      e1A[node * F + c] = (a0 + a1) + (a2 + a3);
    } else { int c = t - 164;
      #pragma unroll
      for (int r = 0; r < F; r += 4) {
        a0 += s_h[r] * eo1w[(F + r) * F + c];       a1 += s_h[r + 1] * eo1w[(F + r + 1) * F + c];
        a2 += s_h[r + 2] * eo1w[(F + r + 2) * F + c]; a3 += s_h[r + 3] * eo1w[(F + r + 3) * F + c];
      }
      e1B[node * F + c] = (a0 + a1) + (a2 + a3);
    }
  }
}

// Fused message-passing step for one (b,i): 512 threads / 8 waves.
// Grid is 512 blocks = 2 blocks/CU; 8 waves/block -> 16 waves/CU = 4 waves/SIMD
// (doubles latency hiding vs the 256-thread version, which sat at VALUBusy 47%).
// amdgpu_waves_per_eu(4,4) pins the 128-VGPR allocation point (avoids round-1's
// 64-VGPR spill disaster). LDS ~74.5 KB/block; 2 blocks/CU still fit in 160 KB.
template<int PRE, int TAIL>
__global__ __attribute__((amdgpu_waves_per_eu(4, 4))) __launch_bounds__(512) void k_mp(
    float* __restrict__ hw, const float* __restrict__ xp,
    const float* __restrict__ hkA_in, const float* __restrict__ hkB_in,
    const float* __restrict__ e1A_in, const float* __restrict__ e1B_in,
    const float* __restrict__ ein_b, const float* __restrict__ rbf_m, const float* __restrict__ rbf_b,
    const float* __restrict__ eo1w, const float* __restrict__ eo1b,
    const float* __restrict__ eo2w, const float* __restrict__ eo2b,
    const float* __restrict__ xmix,
    const float* __restrict__ p1w, const float* __restrict__ p1b,
    const float* __restrict__ p2w, const float* __restrict__ p2b,
    const float* __restrict__ semw, const float* __restrict__ semb,
    const float* __restrict__ n1w, const float* __restrict__ n1b,
    const float* __restrict__ n2w, const float* __restrict__ n2b,
    const float* __restrict__ ein_w,
    float* __restrict__ hkA_out, float* __restrict__ hkB_out,
    float* __restrict__ e1A_out, float* __restrict__ e1B_out,
    const float* __restrict__ c1w, const float* __restrict__ v1w, const float* __restrict__ v1b,
    const float* __restrict__ v2w,
    float* __restrict__ uA, float* __restrict__ uB, float* __restrict__ mbuf) {
  int blk = blockIdx.x, b = blk >> 7, i = blk & 127;
  int t = threadIdx.x, w = t >> 6, lane = t & 63;
  int bN = b * N;
  constexpr float invN = 1.0f / (float)N;

  __shared__ __align__(16) float s_heT[64 * 132];  // he transposed [r][j], pad 132
  __shared__ __align__(16) float s_union[8064];    // t1buf (edge) / post-edge scratch
  __shared__ __align__(16) float4 s_dxn[N];        // (dx0,dx1,dx2,dn)
  __shared__ float s_inv[N];                       // 1/(dn+EPS)
  __shared__ float s_xpos[N * 3];
  __shared__ float s_hi[F];
  __shared__ float s_zkbase[K];
  __shared__ float s_e1base[F];
  __shared__ __align__(16) float s_zk[8][56];
  __shared__ float s_cat[384];
  __shared__ float s_wred[8];
  __shared__ float s_wsum[8];

  float* t1buf   = s_union;          // [64][68]  (edge phase only, 4352)
  float* s_cpart = s_union;          // [8][256][3] = 6144 floats
  float* s_attT  = s_union + 6144;   // [4][128]
  float* s_hcin  = s_union + 6656;   // [256]
  float* s_hEp   = s_union + 6912;   // [2][256]
  float* s_part  = s_union + 7424;   // [8][64]
  float* s_vec   = s_union + 7936;   // [64]
  float* s_hnew  = s_union + 8000;   // [64]

  // ---- staging ----
  for (int idx = t; idx < N * 3; idx += 512) s_xpos[idx] = xp[bN * 3 + idx];
  if (t < F) s_hi[t] = hw[(bN + i) * F + t];
  if (t < K) s_zkbase[t] = hkA_in[(bN + i) * K + t] + ein_b[t];
  if (t >= 64 && t < 128) s_e1base[t - 64] = e1A_in[(bN + i) * F + (t - 64)] + eo1b[t - 64];
  if (lane >= 50 && lane < 56) s_zk[w][lane] = 0.f;  // float4 pad
  __syncthreads();
  if (t < N) {
    float dx0 = s_xpos[i * 3 + 0] - s_xpos[t * 3 + 0];
    float dx1 = s_xpos[i * 3 + 1] - s_xpos[t * 3 + 1];
    float dx2 = s_xpos[i * 3 + 2] - s_xpos[t * 3 + 2];
    float dn = sqrtf(dx0 * dx0 + dx1 * dx1 + dx2 * dx2 + EPS * EPS);
    s_dxn[t] = make_float4(dx0, dx1, dx2, dn);
    s_inv[t] = 1.0f / (dn + EPS);
  }
  __syncthreads();

  float rbm = 0.f, rbb = 0.f;
  if (lane < K) { rbm = rbf_m[lane]; rbb = rbf_b[lane]; }

  // ---- edge phase: waves own contiguous 8-j ranges, two 64-j halves ----
  for (int half = 0; half < 2; ++half) {
    int jbase = half * 64 + w * 8;
    {  // sub-pass A: t1 rows (only wk live)
      float wk[52];
      #pragma unroll
      for (int k = 0; k < 50; ++k) wk[k] = eo1w[(128 + k) * F + lane];
      wk[50] = 0.f; wk[51] = 0.f;
      float w1d = eo1w[178 * F + lane];
      float nhk = (lane < K) ? hkB_in[(bN + jbase) * K + lane] : 0.f;
      float ne1 = e1B_in[(bN + jbase) * F + lane];
      for (int jj = 0; jj < 8; ++jj) {
        int j = jbase + jj;
        float hk = nhk, e1v = ne1;
        if (jj < 7) {
          nhk = (lane < K) ? hkB_in[(bN + j + 1) * K + lane] : 0.f;
          ne1 = e1B_in[(bN + j + 1) * F + lane];
        }
        float dn = s_dxn[j].w;
        if (lane < K) {
          float hkf = s_zkbase[lane] + hk;
          float e = __expf(-dn) - rbm;
          s_zk[w][lane] = __expf(-rbb * e * e) * hkf;
        }
        float ac0 = s_e1base[lane] + e1v + dn * w1d, ac1 = 0.f, ac2 = 0.f, ac3 = 0.f;
        const float4* z4 = (const float4*)(&s_zk[w][0]);
        #pragma unroll
        for (int k4 = 0; k4 < 13; ++k4) {
          float4 z = z4[k4];
          ac0 += z.x * wk[4 * k4];     ac1 += z.y * wk[4 * k4 + 1];
          ac2 += z.z * wk[4 * k4 + 2]; ac3 += z.w * wk[4 * k4 + 3];
        }
        t1buf[(j & 63) * 68 + lane] = silu_f((ac0 + ac1) + (ac2 + ac3));
      }
    }
    // same-wave rows -> no barrier needed
    {  // sub-pass B: he = t1 @ eo2 (only er live), b128-packed writes into he_T
      float er[64];
      #pragma unroll
      for (int r = 0; r < F; ++r) er[r] = eo2w[r * F + lane];
      float b2 = eo2b[lane];
      for (int jj4 = 0; jj4 < 2; ++jj4) {
        float hv[4];
        #pragma unroll
        for (int q = 0; q < 4; ++q) {
          int row = ((jbase + jj4 * 4 + q) & 63) * 68;
          const float4* t4 = (const float4*)(&t1buf[row]);
          float ac0 = b2, ac1 = 0.f, ac2 = 0.f, ac3 = 0.f;
          #pragma unroll
          for (int r4 = 0; r4 < 16; ++r4) {
            float4 tt = t4[r4];
            ac0 += tt.x * er[4 * r4];     ac1 += tt.y * er[4 * r4 + 1];
            ac2 += tt.z * er[4 * r4 + 2]; ac3 += tt.w * er[4 * r4 + 3];
          }
          hv[q] = (ac0 + ac1) + (ac2 + ac3);
        }
        *(float4*)(&s_heT[lane * 132 + jbase + jj4 * 4]) = make_float4(hv[0], hv[1], hv[2], hv[3]);
      }
    }
  }
  __syncthreads();  // he_T complete; t1buf dead -> union becomes scratch

  // ---- coeff phase: register-tiled 8j x 4c, 2 passes; 16 j per thread total ----
  {
    int c0 = 4 * (t & 63);
    float4 aX = make_float4(0.f, 0.f, 0.f, 0.f);
    float4 aY = make_float4(0.f, 0.f, 0.f, 0.f);
    float4 aZ = make_float4(0.f, 0.f, 0.f, 0.f);
    #pragma unroll 1
    for (int p = 0; p < 2; ++p) {
      int j0 = w * 16 + p * 8;
      float4 cacc[8];
      #pragma unroll
      for (int jj = 0; jj < 8; ++jj) cacc[jj] = make_float4(0.f, 0.f, 0.f, 0.f);
      for (int r = 0; r < 64; ++r) {
        float4 xm4 = *(const float4*)(&xmix[r * C + c0]);
        const float4* hb = (const float4*)(&s_heT[r * 132 + j0]);
        float4 h0v = hb[0], h1v = hb[1];
#define CSTEP(idx, hval) \
        cacc[idx].x += (hval) * xm4.x; cacc[idx].y += (hval) * xm4.y; \
        cacc[idx].z += (hval) * xm4.z; cacc[idx].w += (hval) * xm4.w;
        CSTEP(0, h0v.x)  CSTEP(1, h0v.y)  CSTEP(2, h0v.z)  CSTEP(3, h0v.w)
        CSTEP(4, h1v.x)  CSTEP(5, h1v.y)  CSTEP(6, h1v.z)  CSTEP(7, h1v.w)
#undef CSTEP
      }
      #pragma unroll
      for (int jj = 0; jj < 8; ++jj) {
        int j = j0 + jj;
        float4 dq = s_dxn[j];
        float inv = s_inv[j];
        float s0 = tanh_f(cacc[jj].x) * inv;
        float s1 = tanh_f(cacc[jj].y) * inv;
        float s2 = tanh_f(cacc[jj].z) * inv;
        float s3 = tanh_f(cacc[jj].w) * inv;
        aX.x += dq.x * s0; aY.x += dq.y * s0; aZ.x += dq.z * s0;
        aX.y += dq.x * s1; aY.y += dq.y * s1; aZ.y += dq.z * s1;
        aX.z += dq.x * s2; aY.z += dq.y * s2; aZ.z += dq.z * s2;
        aX.w += dq.x * s3; aY.w += dq.y * s3; aZ.w += dq.z * s3;
      }
    }
    int cb = w * 768 + c0 * 3;
    s_cpart[cb + 0] = aX.x; s_cpart[cb + 1] = aY.x; s_cpart[cb + 2]  = aZ.x;
    s_cpart[cb + 3] = aX.y; s_cpart[cb + 4] = aY.y; s_cpart[cb + 5]  = aZ.y;
    s_cpart[cb + 6] = aX.z; s_cpart[cb + 7] = aY.z; s_cpart[cb + 8]  = aZ.z;
    s_cpart[cb + 9] = aX.w; s_cpart[cb + 10] = aY.w; s_cpart[cb + 11] = aZ.w;
  }

  // ---- attention phase: thread t -> (j = t&127, head = t>>7); he_T column reads ----
  {
    int j = t & 127, hh = t >> 7;
    float l0a = 0.f, l0b = 0.f;
    #pragma unroll 8
    for (int r = 0; r < 64; r += 2) {
      float hv0 = s_heT[r * 132 + j];
      float hv1 = s_heT[(r + 1) * 132 + j];
      l0a += hv0 * semw[r * H + hh];
      l0b += hv1 * semw[(r + 1) * H + hh];
    }
    float lg = semb[hh] + l0a + l0b;
    lg = lg > 0.f ? lg : 2.0f * (__expf(0.5f * lg) - 1.0f);  // celu alpha=2
    if (j == i) lg -= 1e5f;
    float m0 = lg;
    #pragma unroll
    for (int off = 32; off > 0; off >>= 1) m0 = fmaxf(m0, __shfl_xor(m0, off));
    if (lane == 0) s_wred[w] = m0;
    __syncthreads();   // also publishes s_cpart
    if (t < 256) {  // hcin combine rides in this gap (8 j-partials)
      int c = t;
      float q0 = 0.f, q1 = 0.f, q2 = 0.f;
      #pragma unroll
      for (int g = 0; g < 8; ++g) {
        q0 += s_cpart[g * 768 + c * 3 + 0];
        q1 += s_cpart[g * 768 + c * 3 + 1];
        q2 += s_cpart[g * 768 + c * 3 + 2];
      }
      q0 *= invN; q1 *= invN; q2 *= invN;
      s_hcin[c] = q0 * q0 + q1 * q1 + q2 * q2;
    }
    // partner wave w^1 covers the other 64 j's of the same head
    float M = fmaxf(s_wred[w], s_wred[w ^ 1]);
    float e = __expf(lg - M);
    float sm = e;
    #pragma unroll
    for (int off = 32; off > 0; off >>= 1) sm += __shfl_xor(sm, off);
    if (lane == 0) s_wsum[w] = sm;
    __syncthreads();
    float S = s_wsum[w] + s_wsum[w ^ 1];
    s_attT[hh * 128 + j] = e / S;
  }
  __syncthreads();

  // ---- h_e phase: idx=(f,head), 2 j-halves; j-contiguous b128 reads ----
  {
    int idx = t & 255, jh = t >> 8;
    int f = idx >> 2, hh = idx & 3;
    const float4* hr = (const float4*)(&s_heT[f * 132 + jh * 64]);
    const float4* ar = (const float4*)(&s_attT[hh * 128 + jh * 64]);
    float ac0 = 0.f, ac1 = 0.f, ac2 = 0.f, ac3 = 0.f;
    #pragma unroll 8
    for (int jg = 0; jg < 16; ++jg) {
      float4 hv = hr[jg];
      float4 av = ar[jg];
      ac0 += hv.x * av.x; ac1 += hv.y * av.y; ac2 += hv.z * av.z; ac3 += hv.w * av.w;
    }
    s_hEp[jh * 256 + idx] = (ac0 + ac1) + (ac2 + ac3);
  }
  __syncthreads();
  if (t < 256) s_cat[64 + t] = s_hEp[t] + s_hEp[256 + t];
  if (t < 64) s_cat[t] = s_hi[t];

  // ---- node phase ----
  {
    int c0 = w * 32;
    float a0 = 0.f, a1 = 0.f, a2 = 0.f, a3 = 0.f;
    #pragma unroll
    for (int cc = 0; cc < 32; cc += 4) {
      a0 += s_hcin[c0 + cc] * p1w[(c0 + cc) * F + lane];
      a1 += s_hcin[c0 + cc + 1] * p1w[(c0 + cc + 1) * F + lane];
      a2 += s_hcin[c0 + cc + 2] * p1w[(c0 + cc + 2) * F + lane];
      a3 += s_hcin[c0 + cc + 3] * p1w[(c0 + cc + 3) * F + lane];
    }
    s_part[w * 64 + lane] = (a0 + a1) + (a2 + a3);
  }
  __syncthreads();
  if (t < F) {
    float s = p1b[t];
    #pragma unroll
    for (int g = 0; g < 8; ++g) s += s_part[g * 64 + t];
    s_vec[t] = silu_f(s);
  }
  __syncthreads();
  if (w < 2) {
    int r0 = w * 32;
    float a0 = 0.f, a1 = 0.f, a2 = 0.f, a3 = 0.f;
    #pragma unroll
    for (int r = 0; r < 32; r += 4) {
      a0 += s_vec[r0 + r] * p2w[(r0 + r) * F + lane];
      a1 += s_vec[r0 + r + 1] * p2w[(r0 + r + 1) * F + lane];
      a2 += s_vec[r0 + r + 2] * p2w[(r0 + r + 2) * F + lane];
      a3 += s_vec[r0 + r + 3] * p2w[(r0 + r + 3) * F + lane];
    }
    s_part[w * 64 + lane] = (a0 + a1) + (a2 + a3);
  }
  __syncthreads();
  if (t < F) s_cat[320 + t] = silu_f(s_part[t] + s_part[64 + t] + p2b[t]);
  __syncthreads();
  {
    int r0 = w * 48;
    float a0 = 0.f, a1 = 0.f, a2 = 0.f, a3 = 0.f;
    #pragma unroll
    for (int rr = 0; rr < 48; rr += 4) {
      a0 += s_cat[r0 + rr] * n1w[(r0 + rr) * F + lane];
      a1 += s_cat[r0 + rr + 1] * n1w[(r0 + rr + 1) * F + lane];
      a2 += s_cat[r0 + rr + 2] * n1w[(r0 + rr + 2) * F + lane];
      a3 += s_cat[r0 + rr + 3] * n1w[(r0 + rr + 3) * F + lane];
    }
    s_part[w * 64 + lane] = (a0 + a1) + (a2 + a3);
  }
  __syncthreads();
  if (t < F) {
    float s = n1b[t];
    #pragma unroll
    for (int g = 0; g < 8; ++g) s += s_part[g * 64 + t];
    s_vec[t] = silu_f(s);
  }
  __syncthreads();
  if (w < 2) {
    int r0 = w * 32;
    float a0 = 0.f, a1 = 0.f, a2 = 0.f, a3 = 0.f;
    #pragma unroll
    for (int r = 0; r < 32; r += 4) {
      a0 += s_vec[r0 + r] * n2w[(r0 + r) * F + lane];
      a1 += s_vec[r0 + r + 1] * n2w[(r0 + r + 1) * F + lane];
      a2 += s_vec[r0 + r + 2] * n2w[(r0 + r + 2) * F + lane];
      a3 += s_vec[r0 + r + 3] * n2w[(r0 + r + 3) * F + lane];
    }
    s_part[w * 64 + lane] = (a0 + a1) + (a2 + a3);
  }
  __syncthreads();
  if (t < F) {
    float hn = s_hi[t] + silu_f(s_part[t] + s_part[64 + t] + n2b[t]);
    s_hnew[t] = hn;
    hw[(bN + i) * F + t] = hn;
  }
  __syncthreads();

  if (PRE) {  // next-step node precomp from updated h
    if (t < 228) {
      float a0 = 0.f, a1 = 0.f, a2 = 0.f, a3 = 0.f;
      if (t < 50) { int k = t;
        #pragma unroll
        for (int r = 0; r < F; r += 4) {
          a0 += s_hnew[r] * ein_w[r * K + k];       a1 += s_hnew[r + 1] * ein_w[(r + 1) * K + k];
          a2 += s_hnew[r + 2] * ein_w[(r + 2) * K + k]; a3 += s_hnew[r + 3] * ein_w[(r + 3) * K + k];
        }
        hkA_out[(bN + i) * K + k] = (a0 + a1) + (a2 + a3);
      } else if (t < 100) { int k = t - 50;
        #pragma unroll
        for (int r = 0; r < F; r += 4) {
          a0 += s_hnew[r] * ein_w[(F + r) * K + k];       a1 += s_hnew[r + 1] * ein_w[(F + r + 1) * K + k];
          a2 += s_hnew[r + 2] * ein_w[(F + r + 2) * K + k]; a3 += s_hnew[r + 3] * ein_w[(F + r + 3) * K + k];
        }
        hkB_out[(bN + i) * K + k] = (a0 + a1) + (a2 + a3);
      } else if (t < 164) { int c = t - 100;
        #pragma unroll
        for (int r = 0; r < F; r += 4) {
          a0 += s_hnew[r] * eo1w[r * F + c];       a1 += s_hnew[r + 1] * eo1w[(r + 1) * F + c];
          a2 += s_hnew[r + 2] * eo1w[(r + 2) * F + c]; a3 += s_hnew[r + 3] * eo1w[(r + 3) * F + c];
        }
        e1A_out[(bN + i) * F + c] = (a0 + a1) + (a2 + a3);
      } else { int c = t - 164;
        #pragma unroll
        for (int r = 0; r < F; r += 4) {
          a0 += s_hnew[r] * eo1w[(F + r) * F + c];       a1 += s_hnew[r + 1] * eo1w[(F + r + 1) * F + c];
          a2 += s_hnew[r + 2] * eo1w[(F + r + 2) * F + c]; a3 += s_hnew[r + 3] * eo1w[(F + r + 3) * F + c];
        }
        e1B_out[(bN + i) * F + c] = (a0 + a1) + (a2 + a3);
      }
    }
  }
  if (TAIL) {  // coord1 halves + vel scalar m for the flow tail
    if (w == 0) {
      float a0 = 0.f, a1 = 0.f, a2 = 0.f, a3 = 0.f;
      #pragma unroll
      for (int r = 0; r < F; r += 4) {
        a0 += s_hnew[r] * c1w[r * F + lane];       a1 += s_hnew[r + 1] * c1w[(r + 1) * F + lane];
        a2 += s_hnew[r + 2] * c1w[(r + 2) * F + lane]; a3 += s_hnew[r + 3] * c1w[(r + 3) * F + lane];
      }
      uA[(bN + i) * F + lane] = (a0 + a1) + (a2 + a3);
    } else if (w == 1) {
      float a0 = 0.f, a1 = 0.f, a2 = 0.f, a3 = 0.f;
      #pragma unroll
      for (int r = 0; r < F; r += 4) {
        a0 += s_hnew[r] * c1w[(F + r) * F + lane];       a1 += s_hnew[r + 1] * c1w[(F + r + 1) * F + lane];
        a2 += s_hnew[r + 2] * c1w[(F + r + 2) * F + lane]; a3 += s_hnew[r + 3] * c1w[(F + r + 3) * F + lane];
      }
      uB[(bN + i) * F + lane] = (a0 + a1) + (a2 + a3);
    } else if (w == 2) {
      float a0 = v1b[lane], a1 = 0.f, a2 = 0.f, a3 = 0.f;
      #pragma unroll
      for (int r = 0; r < F; r += 4) {
        a0 += s_hnew[r] * v1w[r * F + lane];       a1 += s_hnew[r + 1] * v1w[(r + 1) * F + lane];
        a2 += s_hnew[r + 2] * v1w[(r + 2) * F + lane]; a3 += s_hnew[r + 3] * v1w[(r + 3) * F + lane];
      }
      float tv = silu_f((a0 + a1) + (a2 + a3)) * v2w[lane];
      #pragma unroll
      for (int off = 32; off > 0; off >>= 1) tv += __shfl_down(tv, off);
      if (lane == 0) mbuf[bN + i] = tv;
    }
  }
}

// delta_v[b,i] = (1/N) sum_j (coord2 . silu(uA_i + uB_j + b)) * (x_i - x_j)
__global__ __launch_bounds__(256) void k_tail(const float* __restrict__ xb,
    const float* __restrict__ uA, const float* __restrict__ uB,
    const float* __restrict__ c1b, const float* __restrict__ c2w,
    float* __restrict__ dv) {
  int blk = blockIdx.x, b = blk >> 7, i = blk & 127;
  int t = threadIdx.x, w = t >> 6, lane = t & 63;
  __shared__ float s_xpos[N * 3];
  __shared__ float s_uAi[F];
  __shared__ float s_acc[4][3];
  for (int idx = t; idx < N * 3; idx += 256) s_xpos[idx] = xb[b * N * 3 + idx];
  if (t < F) s_uAi[t] = uA[(b * N + i) * F + t];
  __syncthreads();
  float xi0 = s_xpos[i * 3 + 0], xi1 = s_xpos[i * 3 + 1], xi2 = s_xpos[i * 3 + 2];
  float base = s_uAi[lane] + c1b[lane];
  float c2v = c2w[lane];
  float a0 = 0.f, a1 = 0.f, a2 = 0.f;
  for (int jj = 0; jj < 32; ++jj) {
    int j = w + 4 * jj;
    float tv = silu_f(base + uB[(b * N + j) * F + lane]) * c2v;
    #pragma unroll
    for (int off = 32; off > 0; off >>= 1) tv += __shfl_down(tv, off);
    if (lane == 0) {
      float dx0 = xi0 - s_xpos[j * 3 + 0];
      float dx1 = xi1 - s_xpos[j * 3 + 1];
      float dx2 = xi2 - s_xpos[j * 3 + 2];
      a0 += tv * dx0; a1 += tv * dx1; a2 += tv * dx2;
    }
  }
  if (lane == 0) { s_acc[w][0] = a0; s_acc[w][1] = a1; s_acc[w][2] = a2; }
  __syncthreads();
  if (t < 3) {
    float s = s_acc[0][t] + s_acc[1][t] + s_acc[2][t] + s_acc[3][t];
    dv[(b * N + i) * 3 + t] = s * (1.0f / (float)N);
  }
}

// apply v' = exp(m)*v + dv, x' = x + v'; center x and v; sld += 3*sum(m). One block per batch.
__global__ __launch_bounds__(128) void k_fin(float* __restrict__ xb, float* __restrict__ vb,
    const float* __restrict__ dv, const float* __restrict__ mbuf, float* __restrict__ sld) {
  int b = blockIdx.x, t = threadIdx.x;
  __shared__ float red[N];
  float m = mbuf[b * N + t];
  float em = __expf(m);
  float vv[3], xx[3];
  #pragma unroll
  for (int d = 0; d < 3; ++d) {
    int idx = (b * N + t) * 3 + d;
    vv[d] = em * vb[idx] + dv[idx];
    xx[d] = xb[idx] + vv[d];
  }
  #pragma unroll
  for (int d = 0; d < 3; ++d) {
    red[t] = xx[d];
    __syncthreads();
    for (int s = 64; s > 0; s >>= 1) { if (t < s) red[t] += red[t + s]; __syncthreads(); }
    xx[d] -= red[0] * (1.0f / (float)N);
    __syncthreads();
    red[t] = vv[d];
    __syncthreads();
    for (int s = 64; s > 0; s >>= 1) { if (t < s) red[t] += red[t + s]; __syncthreads(); }
    vv[d] -= red[0] * (1.0f / (float)N);
    __syncthreads();
  }
  #pragma unroll
  for (int d = 0; d < 3; ++d) {
    int idx = (b * N + t) * 3 + d;
    xb[idx] = xx[d];
    vb[idx] = vv[d];
  }
  red[t] = m;
  __syncthreads();
  for (int s = 64; s > 0; s >>= 1) { if (t < s) red[t] += red[t + s]; __syncthreads(); }
  if (t == 0) sld[b] += 3.0f * red[0];
}

__global__ void k_out(const float* __restrict__ xw, const float* __restrict__ vw,
                      const float* __restrict__ sld, float* __restrict__ out) {
  int t = blockIdx.x * blockDim.x + threadIdx.x;
  if (t < B * N * 3) { out[t] = xw[t]; out[B * N * 3 + t] = vw[t]; }
  if (t < B) out[2 * B * N * 3 + t] = sld[t];
}

}  // namespace

extern "C" void kernel_launch(void* const* d_in, const int* in_sizes, int n_in,
                              void* d_out, int out_size, void* d_ws, size_t ws_size,
                              hipStream_t stream) {
  const float* in_h   = (const float*)d_in[0];
  const float* in_x   = (const float*)d_in[1];
  const float* in_v   = (const float*)d_in[2];
  const float* emb1_w = (const float*)d_in[3];
  const float* emb1_b = (const float*)d_in[4];
  const float* emb2_w = (const float*)d_in[5];
  const float* emb2_b = (const float*)d_in[6];
  const float* ein_w  = (const float*)d_in[7];
  const float* ein_b  = (const float*)d_in[8];
  const float* rbf_m  = (const float*)d_in[9];
  const float* rbf_b  = (const float*)d_in[10];
  const float* eo1w   = (const float*)d_in[11];
  const float* eo1b   = (const float*)d_in[12];
  const float* eo2w   = (const float*)d_in[13];
  const float* eo2b   = (const float*)d_in[14];
  const float* xmix   = (const float*)d_in[15];
  const float* p1w    = (const float*)d_in[16];
  const float* p1b    = (const float*)d_in[17];
  const float* p2w    = (const float*)d_in[18];
  const float* p2b    = (const float*)d_in[19];
  const float* semw   = (const float*)d_in[20];
  const float* semb   = (const float*)d_in[21];
  const float* n1w    = (const float*)d_in[22];
  const float* n1b    = (const float*)d_in[23];
  const float* n2w    = (const float*)d_in[24];
  const float* n2b    = (const float*)d_in[25];
  const float* v1w    = (const float*)d_in[26];
  const float* v1b    = (const float*)d_in[27];
  const float* v2w    = (const float*)d_in[28];
  const float* c1w    = (const float*)d_in[29];
  const float* c1b    = (const float*)d_in[30];
  const float* c2w    = (const float*)d_in[31];

  float* ws   = (float*)d_ws;
  float* h0   = ws;                 // BN*F
  float* hw   = h0 + BN * F;        // BN*F
  float* hkA0 = hw + BN * F;        // BN*K
  float* hkB0 = hkA0 + BN * K;
  float* e1A0 = hkB0 + BN * K;      // BN*F
  float* e1B0 = e1A0 + BN * F;
  float* hkA1 = e1B0 + BN * F;
  float* hkB1 = hkA1 + BN * K;
  float* e1A1 = hkB1 + BN * K;
  float* e1B1 = e1A1 + BN * F;
  float* uA   = e1B1 + BN * F;      // BN*F
  float* uB   = uA + BN * F;
  float* xw   = uB + BN * F;        // BN*3
  float* vw   = xw + BN * 3;
  float* dvb  = vw + BN * 3;
  float* mbuf = dvb + BN * 3;       // BN
  float* sld  = mbuf + BN;          // B

  k_init<<<6, 256, 0, stream>>>(in_x, in_v, xw, vw, sld);
  k_embed<<<BN, F, 0, stream>>>(in_h, emb1_w, emb1_b, emb2_w, emb2_b, h0);

  float* hkA[2] = {hkA0, hkA1};
  float* hkB[2] = {hkB0, hkB1};
  float* e1A[2] = {e1A0, e1A1};
  float* e1B[2] = {e1B0, e1B1};

  for (int dep = 0; dep < 2; ++dep) {
    for (int half = 0; half < 2; ++half) {
      int l = 2 * dep + half;
      float* xb = half ? vw : xw;
      float* vb = half ? xw : vw;
      const float* einw_l = ein_w + l * 2 * F * K;
      const float* einb_l = ein_b + l * K;
      const float* rbm_l  = rbf_m + l * K;
      const float* rbb_l  = rbf_b + l * K;
      const float* eo1w_l = eo1w + l * 179 * F;
      const float* eo1b_l = eo1b + l * F;
      const float* eo2w_l = eo2w + l * F * F;
      const float* eo2b_l = eo2b + l * F;
      const float* xmix_l = xmix + l * F * C;
      const float* p1w_l  = p1w + l * C * F;
      const float* p1b_l  = p1b + l * F;
      const float* p2w_l  = p2w + l * F * F;
      const float* p2b_l  = p2b + l * F;
      const float* semw_l = semw + l * F * H;
      const float* semb_l = semb + l * H;
      const float* n1w_l  = n1w + l * 384 * F;
      const float* n1b_l  = n1b + l * F;
      const float* n2w_l  = n2w + l * F * F;
      const float* n2b_l  = n2b + l * F;
      const float* v1w_l  = v1w + l * F * F;
      const float* v1b_l  = v1b + l * F;
      const float* v2w_l  = v2w + l * F;
      const float* c1w_l  = c1w + l * 2 * F * F;
      const float* c1b_l  = c1b + l * F;
      const float* c2w_l  = c2w + l * F;

      k_pre<<<BN, 256, 0, stream>>>(h0, hw, einw_l, eo1w_l, hkA[0], hkB[0], e1A[0], e1B[0]);
      // step 0: in set0 -> out set1 ; step 1: in set1 -> out set0 ; step 2: in set0, tail
      k_mp<1, 0><<<BN, 512, 0, stream>>>(hw, xb, hkA[0], hkB[0], e1A[0], e1B[0],
          einb_l, rbm_l, rbb_l, eo1w_l, eo1b_l, eo2w_l, eo2b_l, xmix_l,
          p1w_l, p1b_l, p2w_l, p2b_l, semw_l, semb_l, n1w_l, n1b_l, n2w_l, n2b_l,
          einw_l, hkA[1], hkB[1], e1A[1], e1B[1],
          c1w_l, v1w_l, v1b_l, v2w_l, uA, uB, mbuf);
      k_mp<1, 0><<<BN, 512, 0, stream>>>(hw, xb, hkA[1], hkB[1], e1A[1], e1B[1],
          einb_l, rbm_l, rbb_l, eo1w_l, eo1b_l, eo2w_l, eo2b_l, xmix_l,
          p1w_l, p1b_l, p2w_l, p2b_l, semw_l, semb_l, n1w_l, n1b_l, n2w_l, n2b_l,
          einw_l, hkA[0], hkB[0], e1A[0], e1B[0],
          c1w_l, v1w_l, v1b_l, v2w_l, uA, uB, mbuf);
      k_mp<0, 1><<<BN, 512, 0, stream>>>(hw, xb, hkA[0], hkB[0], e1A[0], e1B[0],
          einb_l, rbm_l, rbb_l, eo1w_l, eo1b_l, eo2w_l, eo2b_l, xmix_l,
          p1w_l, p1b_l, p2w_l, p2b_l, semw_l, semb_l, n1w_l, n1b_l, n2w_l, n2b_l,
          einw_l, hkA[1], hkB[1], e1A[1], e1B[1],
          c1w_l, v1w_l, v1b_l, v2w_l, uA, uB, mbuf);
      k_tail<<<BN, 256, 0, stream>>>(xb, uA, uB, c1b_l, c2w_l, dvb);
      k_fin<<<B, 128, 0, stream>>>(xb, vb, dvb, mbuf, sld);
    }
  }
  k_out<<<6, 256, 0, stream>>>(xw, vw, sld, (float*)d_out);
}

// Round 7
// 2529.492 us; speedup vs baseline: 1.5661x; 1.5661x over previous
//
#include <hip/hip_runtime.h>
#include <math.h>

namespace {

constexpr int B = 4, N = 128, FIN = 16, F = 64, H = 4, K = 50, C = 256;
constexpr int BN = B * N;
constexpr float EPS = 1e-5f;

__device__ __forceinline__ float silu_f(float x) { return x / (1.0f + __expf(-x)); }
__device__ __forceinline__ float tanh_f(float x) { return 1.0f - 2.0f / (__expf(2.0f * x) + 1.0f); }

__global__ void k_init(const float* __restrict__ x, const float* __restrict__ v,
                       float* __restrict__ xw, float* __restrict__ vw, float* __restrict__ sld) {
  int t = blockIdx.x * blockDim.x + threadIdx.x;
  if (t < B * N * 3) { xw[t] = x[t]; vw[t] = v[t]; }
  if (t < B) sld[t] = 0.0f;
}

__global__ __launch_bounds__(F) void k_embed(const float* __restrict__ hin,
    const float* __restrict__ w1, const float* __restrict__ b1,
    const float* __restrict__ w2, const float* __restrict__ b2, float* __restrict__ h0) {
  int node = blockIdx.x, f = threadIdx.x;
  __shared__ float t1[F];
  float acc = b1[f];
  #pragma unroll
  for (int r = 0; r < FIN; ++r) acc += hin[node * FIN + r] * w1[r * F + f];
  t1[f] = silu_f(acc);
  __syncthreads();
  float a0 = b2[f], a1 = 0.f, a2 = 0.f, a3 = 0.f;
  #pragma unroll
  for (int r = 0; r < F; r += 4) {
    a0 += t1[r] * w2[r * F + f];
    a1 += t1[r + 1] * w2[(r + 1) * F + f];
    a2 += t1[r + 2] * w2[(r + 2) * F + f];
    a3 += t1[r + 3] * w2[(r + 3) * F + f];
  }
  h0[node * F + f] = (a0 + a1) + (a2 + a3);
}

// Per-node precomputation at flow start: hkA/hkB (edge_in halves), e1A/e1B (eo1 halves).
__global__ __launch_bounds__(256) void k_pre(const float* __restrict__ h0, float* __restrict__ hw,
    const float* __restrict__ ein_w, const float* __restrict__ eo1w,
    float* __restrict__ hkA, float* __restrict__ hkB,
    float* __restrict__ e1A, float* __restrict__ e1B) {
  int node = blockIdx.x, t = threadIdx.x;
  __shared__ float s_h[F];
  if (t < F) s_h[t] = h0[node * F + t];
  __syncthreads();
  if (t < F) hw[node * F + t] = s_h[t];
  if (t < 228) {
    float a0 = 0.f, a1 = 0.f, a2 = 0.f, a3 = 0.f;
    if (t < 50) { int k = t;
      #pragma unroll
      for (int r = 0; r < F; r += 4) {
        a0 += s_h[r] * ein_w[r * K + k];       a1 += s_h[r + 1] * ein_w[(r + 1) * K + k];
        a2 += s_h[r + 2] * ein_w[(r + 2) * K + k]; a3 += s_h[r + 3] * ein_w[(r + 3) * K + k];
      }
      hkA[node * K + k] = (a0 + a1) + (a2 + a3);
    } else if (t < 100) { int k = t - 50;
      #pragma unroll
      for (int r = 0; r < F; r += 4) {
        a0 += s_h[r] * ein_w[(F + r) * K + k];       a1 += s_h[r + 1] * ein_w[(F + r + 1) * K + k];
        a2 += s_h[r + 2] * ein_w[(F + r + 2) * K + k]; a3 += s_h[r + 3] * ein_w[(F + r + 3) * K + k];
      }
      hkB[node * K + k] = (a0 + a1) + (a2 + a3);
    } else if (t < 164) { int c = t - 100;
      #pragma unroll
      for (int r = 0; r < F; r += 4) {
        a0 += s_h[r] * eo1w[r * F + c];       a1 += s_h[r + 1] * eo1w[(r + 1) * F + c];
        a2 += s_h[r + 2] * eo1w[(r + 2) * F + c]; a3 += s_h[r + 3] * eo1w[(r + 3) * F + c];
      }
      e1A[node * F + c] = (a0 + a1) + (a2 + a3);
    } else { int c = t - 164;
      #pragma unroll
      for (int r = 0; r < F; r += 4) {
        a0 += s_h[r] * eo1w[(F + r) * F + c];       a1 += s_h[r + 1] * eo1w[(F + r + 1) * F + c];
        a2 += s_h[r + 2] * eo1w[(F + r + 2) * F + c]; a3 += s_h[r + 3] * eo1w[(F + r + 3) * F + c];
      }
      e1B[node * F + c] = (a0 + a1) + (a2 + a3);
    }
  }
}

// Heavy half-step kernel: one block per (b, i, j-half). 256 threads / 4 waves.
// Grid = BN*2 = 1024 blocks = 4 blocks/CU -> 16 waves/CU (2x round-5 occupancy).
// Computes edge MLP for 64 j's, coeff partial sums, logits + local-max exp/sum,
// and U = sum_j e_j*he_j (flash-style softmax split). he never leaves LDS.
__global__ __launch_bounds__(256, 4) void k_edge(
    const float* __restrict__ xp,
    const float* __restrict__ hkA_in, const float* __restrict__ hkB_in,
    const float* __restrict__ e1A_in, const float* __restrict__ e1B_in,
    const float* __restrict__ ein_b, const float* __restrict__ rbf_m, const float* __restrict__ rbf_b,
    const float* __restrict__ eo1w, const float* __restrict__ eo1b,
    const float* __restrict__ eo2w, const float* __restrict__ eo2b,
    const float* __restrict__ xmix,
    const float* __restrict__ semw, const float* __restrict__ semb,
    float* __restrict__ mS, float* __restrict__ Upart, float* __restrict__ combpart) {
  int blk = blockIdx.x;
  int b = blk >> 8, i = (blk >> 1) & 127, jh = blk & 1;
  int t = threadIdx.x, w = t >> 6, lane = t & 63;
  int bN = b * N;
  int bi2 = ((bN + i) << 1) + jh;

  __shared__ __align__(16) float s_heT[64 * 68];   // he transposed [r][j_local], pad 68
  __shared__ __align__(16) float s_union[4352];    // t1buf (edge) / {cpart, att}
  __shared__ __align__(16) float4 s_dxn[64];       // (dx0,dx1,dx2,dn) for local j
  __shared__ float s_inv[64];
  __shared__ float s_xpos[N * 3];
  __shared__ float s_zkbase[K];
  __shared__ float s_e1base[F];
  __shared__ __align__(16) float s_zk[4][56];

  float* t1buf   = s_union;          // [64][68] during edge
  float* s_cpart = s_union;          // [4][256][3] = 3072 after edge
  float* s_att   = s_union + 3072;   // [4][64] unnormalized e

  // ---- staging ----
  for (int idx = t; idx < N * 3; idx += 256) s_xpos[idx] = xp[bN * 3 + idx];
  if (t < K) s_zkbase[t] = hkA_in[(bN + i) * K + t] + ein_b[t];
  if (t >= 64 && t < 128) s_e1base[t - 64] = e1A_in[(bN + i) * F + (t - 64)] + eo1b[t - 64];
  if (lane >= 50 && lane < 56) s_zk[w][lane] = 0.f;  // float4 pad
  __syncthreads();
  if (t < 64) {
    int jg = jh * 64 + t;
    float dx0 = s_xpos[i * 3 + 0] - s_xpos[jg * 3 + 0];
    float dx1 = s_xpos[i * 3 + 1] - s_xpos[jg * 3 + 1];
    float dx2 = s_xpos[i * 3 + 2] - s_xpos[jg * 3 + 2];
    float dn = sqrtf(dx0 * dx0 + dx1 * dx1 + dx2 * dx2 + EPS * EPS);
    s_dxn[t] = make_float4(dx0, dx1, dx2, dn);
    s_inv[t] = 1.0f / (dn + EPS);
  }
  __syncthreads();

  float rbm = 0.f, rbb = 0.f;
  if (lane < K) { rbm = rbf_m[lane]; rbb = rbf_b[lane]; }

  // ---- edge phase: wave w owns local j in [w*16, w*16+16) ----
  {
    int jbl = w * 16;               // local base
    int jbg = jh * 64 + jbl;        // global base
    {  // sub-pass A: t1 rows (only wk live)
      float wk[52];
      #pragma unroll
      for (int k = 0; k < 50; ++k) wk[k] = eo1w[(128 + k) * F + lane];
      wk[50] = 0.f; wk[51] = 0.f;
      float w1d = eo1w[178 * F + lane];
      float nhk = (lane < K) ? hkB_in[(bN + jbg) * K + lane] : 0.f;
      float ne1 = e1B_in[(bN + jbg) * F + lane];
      for (int jj = 0; jj < 16; ++jj) {
        int jl = jbl + jj;
        float hk = nhk, e1v = ne1;
        if (jj < 15) {
          nhk = (lane < K) ? hkB_in[(bN + jbg + jj + 1) * K + lane] : 0.f;
          ne1 = e1B_in[(bN + jbg + jj + 1) * F + lane];
        }
        float dn = s_dxn[jl].w;
        if (lane < K) {
          float hkf = s_zkbase[lane] + hk;
          float e = __expf(-dn) - rbm;
          s_zk[w][lane] = __expf(-rbb * e * e) * hkf;
        }
        float ac0 = s_e1base[lane] + e1v + dn * w1d, ac1 = 0.f, ac2 = 0.f, ac3 = 0.f;
        const float4* z4 = (const float4*)(&s_zk[w][0]);
        #pragma unroll
        for (int k4 = 0; k4 < 13; ++k4) {
          float4 z = z4[k4];
          ac0 += z.x * wk[4 * k4];     ac1 += z.y * wk[4 * k4 + 1];
          ac2 += z.z * wk[4 * k4 + 2]; ac3 += z.w * wk[4 * k4 + 3];
        }
        t1buf[jl * 68 + lane] = silu_f((ac0 + ac1) + (ac2 + ac3));
      }
    }
    // same-wave rows -> no barrier needed
    {  // sub-pass B: he = t1 @ eo2 (only er live), b128-packed writes into he_T
      float er[64];
      #pragma unroll
      for (int r = 0; r < F; ++r) er[r] = eo2w[r * F + lane];
      float b2 = eo2b[lane];
      for (int jj4 = 0; jj4 < 4; ++jj4) {
        float hv[4];
        #pragma unroll
        for (int q = 0; q < 4; ++q) {
          const float4* t4 = (const float4*)(&t1buf[(jbl + jj4 * 4 + q) * 68]);
          float ac0 = b2, ac1 = 0.f, ac2 = 0.f, ac3 = 0.f;
          #pragma unroll
          for (int r4 = 0; r4 < 16; ++r4) {
            float4 tt = t4[r4];
            ac0 += tt.x * er[4 * r4];     ac1 += tt.y * er[4 * r4 + 1];
            ac2 += tt.z * er[4 * r4 + 2]; ac3 += tt.w * er[4 * r4 + 3];
          }
          hv[q] = (ac0 + ac1) + (ac2 + ac3);
        }
        *(float4*)(&s_heT[lane * 68 + jbl + jj4 * 4]) = make_float4(hv[0], hv[1], hv[2], hv[3]);
      }
    }
  }
  __syncthreads();  // he_T complete; t1buf dead -> union becomes cpart/att

  // ---- coeff partial: register-tiled 8j x 4c, 2 passes over this wave's 16 j ----
  {
    int c0 = 4 * (t & 63);
    float4 aX = make_float4(0.f, 0.f, 0.f, 0.f);
    float4 aY = make_float4(0.f, 0.f, 0.f, 0.f);
    float4 aZ = make_float4(0.f, 0.f, 0.f, 0.f);
    #pragma unroll 1
    for (int p = 0; p < 2; ++p) {
      int j0 = w * 16 + p * 8;   // local j
      float4 cacc[8];
      #pragma unroll
      for (int jj = 0; jj < 8; ++jj) cacc[jj] = make_float4(0.f, 0.f, 0.f, 0.f);
      for (int r = 0; r < 64; ++r) {
        float4 xm4 = *(const float4*)(&xmix[r * C + c0]);
        const float4* hb = (const float4*)(&s_heT[r * 68 + j0]);
        float4 h0v = hb[0], h1v = hb[1];
#define CSTEP(idx, hval) \
        cacc[idx].x += (hval) * xm4.x; cacc[idx].y += (hval) * xm4.y; \
        cacc[idx].z += (hval) * xm4.z; cacc[idx].w += (hval) * xm4.w;
        CSTEP(0, h0v.x)  CSTEP(1, h0v.y)  CSTEP(2, h0v.z)  CSTEP(3, h0v.w)
        CSTEP(4, h1v.x)  CSTEP(5, h1v.y)  CSTEP(6, h1v.z)  CSTEP(7, h1v.w)
#undef CSTEP
      }
      #pragma unroll
      for (int jj = 0; jj < 8; ++jj) {
        int jl = j0 + jj;
        float4 dq = s_dxn[jl];
        float inv = s_inv[jl];
        float s0 = tanh_f(cacc[jj].x) * inv;
        float s1 = tanh_f(cacc[jj].y) * inv;
        float s2 = tanh_f(cacc[jj].z) * inv;
        float s3 = tanh_f(cacc[jj].w) * inv;
        aX.x += dq.x * s0; aY.x += dq.y * s0; aZ.x += dq.z * s0;
        aX.y += dq.x * s1; aY.y += dq.y * s1; aZ.y += dq.z * s1;
        aX.z += dq.x * s2; aY.z += dq.y * s2; aZ.z += dq.z * s2;
        aX.w += dq.x * s3; aY.w += dq.y * s3; aZ.w += dq.z * s3;
      }
    }
    int cb = w * 768 + c0 * 3;
    s_cpart[cb + 0] = aX.x; s_cpart[cb + 1] = aY.x; s_cpart[cb + 2]  = aZ.x;
    s_cpart[cb + 3] = aX.y; s_cpart[cb + 4] = aY.y; s_cpart[cb + 5]  = aZ.y;
    s_cpart[cb + 6] = aX.z; s_cpart[cb + 7] = aY.z; s_cpart[cb + 8]  = aZ.z;
    s_cpart[cb + 9] = aX.w; s_cpart[cb + 10] = aY.w; s_cpart[cb + 11] = aZ.w;
  }
  __syncthreads();

  // ---- combine the 4 wave partials of comb -> global ----
  {
    int c = t;
    float q0 = s_cpart[c * 3 + 0] + s_cpart[768 + c * 3 + 0] + s_cpart[1536 + c * 3 + 0] + s_cpart[2304 + c * 3 + 0];
    float q1 = s_cpart[c * 3 + 1] + s_cpart[768 + c * 3 + 1] + s_cpart[1536 + c * 3 + 1] + s_cpart[2304 + c * 3 + 1];
    float q2 = s_cpart[c * 3 + 2] + s_cpart[768 + c * 3 + 2] + s_cpart[1536 + c * 3 + 2] + s_cpart[2304 + c * 3 + 2];
    combpart[bi2 * 768 + c * 3 + 0] = q0;
    combpart[bi2 * 768 + c * 3 + 1] = q1;
    combpart[bi2 * 768 + c * 3 + 2] = q2;
  }

  // ---- logits: thread t -> (j_local = t&63, head = t>>6 = w); column reads ----
  {
    int jl = t & 63, hh = w;
    int jg = jh * 64 + jl;
    float l0a = 0.f, l0b = 0.f;
    #pragma unroll 8
    for (int r = 0; r < 64; r += 2) {
      float hv0 = s_heT[r * 68 + jl];
      float hv1 = s_heT[(r + 1) * 68 + jl];
      l0a += hv0 * semw[r * H + hh];
      l0b += hv1 * semw[(r + 1) * H + hh];
    }
    float lg = semb[hh] + l0a + l0b;
    lg = lg > 0.f ? lg : 2.0f * (__expf(0.5f * lg) - 1.0f);  // celu alpha=2
    if (jg == i) lg -= 1e5f;
    float m = lg;
    #pragma unroll
    for (int off = 32; off > 0; off >>= 1) m = fmaxf(m, __shfl_xor(m, off));
    float e = __expf(lg - m);
    float S = e;
    #pragma unroll
    for (int off = 32; off > 0; off >>= 1) S += __shfl_xor(S, off);
    s_att[hh * 64 + jl] = e;
    if (lane == 0) { mS[bi2 * 8 + hh * 2] = m; mS[bi2 * 8 + hh * 2 + 1] = S; }
  }
  __syncthreads();

  // ---- U partial: thread t -> (f = t>>2, head = t&3); j-contiguous b128 reads ----
  {
    int f = t >> 2, hh = t & 3;
    const float4* hr = (const float4*)(&s_heT[f * 68]);
    const float4* ar = (const float4*)(&s_att[hh * 64]);
    float ac0 = 0.f, ac1 = 0.f, ac2 = 0.f, ac3 = 0.f;
    #pragma unroll 8
    for (int jg4 = 0; jg4 < 16; ++jg4) {
      float4 hv = hr[jg4];
      float4 av = ar[jg4];
      ac0 += hv.x * av.x; ac1 += hv.y * av.y; ac2 += hv.z * av.z; ac3 += hv.w * av.w;
    }
    Upart[bi2 * 256 + t] = (ac0 + ac1) + (ac2 + ac3);
  }
}

// Light combine kernel: one block per (b,i). Rescale-combine softmax halves,
// hcin, node MLPs + residual, plus PRE (next-step precomp) or TAIL outputs.
template<int PRE, int TAIL>
__global__ __launch_bounds__(256, 2) void k_comb(
    float* __restrict__ hw,
    const float* __restrict__ mS, const float* __restrict__ Upart, const float* __restrict__ combpart,
    const float* __restrict__ p1w, const float* __restrict__ p1b,
    const float* __restrict__ p2w, const float* __restrict__ p2b,
    const float* __restrict__ n1w, const float* __restrict__ n1b,
    const float* __restrict__ n2w, const float* __restrict__ n2b,
    const float* __restrict__ ein_w, const float* __restrict__ eo1w,
    float* __restrict__ hkA_out, float* __restrict__ hkB_out,
    float* __restrict__ e1A_out, float* __restrict__ e1B_out,
    const float* __restrict__ c1w, const float* __restrict__ v1w, const float* __restrict__ v1b,
    const float* __restrict__ v2w,
    float* __restrict__ uA, float* __restrict__ uB, float* __restrict__ mbuf) {
  int blk = blockIdx.x, b = blk >> 7, i = blk & 127;
  int t = threadIdx.x, w = t >> 6, lane = t & 63;
  int bN = b * N;
  int bi2 = (bN + i) << 1;
  constexpr float invN = 1.0f / (float)N;

  __shared__ float s_hcin[C];
  __shared__ float s_cat[384];
  __shared__ float s_part[4][F];
  __shared__ float s_vec[F];
  __shared__ float s_hnew[F];

  float hi_val = (t < F) ? hw[(bN + i) * F + t] : 0.f;

  // ---- h_e combine (flash-style rescale) ----
  {
    int hh = t & 3;
    float m0 = mS[bi2 * 8 + hh * 2],       S0 = mS[bi2 * 8 + hh * 2 + 1];
    float m1 = mS[(bi2 + 1) * 8 + hh * 2], S1 = mS[(bi2 + 1) * 8 + hh * 2 + 1];
    float m = fmaxf(m0, m1);
    float w0 = __expf(m0 - m), w1 = __expf(m1 - m);
    float u = w0 * Upart[bi2 * 256 + t] + w1 * Upart[(bi2 + 1) * 256 + t];
    s_cat[64 + t] = u / (w0 * S0 + w1 * S1);
  }
  // ---- hcin combine ----
  {
    int c = t;
    float q0 = (combpart[bi2 * 768 + c * 3 + 0] + combpart[(bi2 + 1) * 768 + c * 3 + 0]) * invN;
    float q1 = (combpart[bi2 * 768 + c * 3 + 1] + combpart[(bi2 + 1) * 768 + c * 3 + 1]) * invN;
    float q2 = (combpart[bi2 * 768 + c * 3 + 2] + combpart[(bi2 + 1) * 768 + c * 3 + 2]) * invN;
    s_hcin[c] = q0 * q0 + q1 * q1 + q2 * q2;
  }
  __syncthreads();

  // ---- node phase (proven 256-thread version) ----
  {
    int c0 = w * 64;
    float a0 = 0.f, a1 = 0.f, a2 = 0.f, a3 = 0.f;
    #pragma unroll 8
    for (int cc = 0; cc < 64; cc += 4) {
      a0 += s_hcin[c0 + cc] * p1w[(c0 + cc) * F + lane];
      a1 += s_hcin[c0 + cc + 1] * p1w[(c0 + cc + 1) * F + lane];
      a2 += s_hcin[c0 + cc + 2] * p1w[(c0 + cc + 2) * F + lane];
      a3 += s_hcin[c0 + cc + 3] * p1w[(c0 + cc + 3) * F + lane];
    }
    s_part[w][lane] = (a0 + a1) + (a2 + a3);
  }
  __syncthreads();
  if (t < F) s_vec[t] = silu_f(s_part[0][t] + s_part[1][t] + s_part[2][t] + s_part[3][t] + p1b[t]);
  __syncthreads();
  if (t < F) {
    float a0 = p2b[t], a1 = 0.f, a2 = 0.f, a3 = 0.f;
    #pragma unroll 8
    for (int r = 0; r < F; r += 4) {
      a0 += s_vec[r] * p2w[r * F + t];
      a1 += s_vec[r + 1] * p2w[(r + 1) * F + t];
      a2 += s_vec[r + 2] * p2w[(r + 2) * F + t];
      a3 += s_vec[r + 3] * p2w[(r + 3) * F + t];
    }
    s_cat[t] = hi_val;
    s_cat[320 + t] = silu_f((a0 + a1) + (a2 + a3));
  }
  __syncthreads();
  {
    int r0 = w * 96;
    float a0 = 0.f, a1 = 0.f, a2 = 0.f, a3 = 0.f;
    #pragma unroll 8
    for (int rr = 0; rr < 96; rr += 4) {
      a0 += s_cat[r0 + rr] * n1w[(r0 + rr) * F + lane];
      a1 += s_cat[r0 + rr + 1] * n1w[(r0 + rr + 1) * F + lane];
      a2 += s_cat[r0 + rr + 2] * n1w[(r0 + rr + 2) * F + lane];
      a3 += s_cat[r0 + rr + 3] * n1w[(r0 + rr + 3) * F + lane];
    }
    s_part[w][lane] = (a0 + a1) + (a2 + a3);
  }
  __syncthreads();
  if (t < F) s_vec[t] = silu_f(s_part[0][t] + s_part[1][t] + s_part[2][t] + s_part[3][t] + n1b[t]);
  __syncthreads();
  if (t < F) {
    float a0 = n2b[t], a1 = 0.f, a2 = 0.f, a3 = 0.f;
    #pragma unroll 8
    for (int r = 0; r < F; r += 4) {
      a0 += s_vec[r] * n2w[r * F + t];
      a1 += s_vec[r + 1] * n2w[(r + 1) * F + t];
      a2 += s_vec[r + 2] * n2w[(r + 2) * F + t];
      a3 += s_vec[r + 3] * n2w[(r + 3) * F + t];
    }
    float hn = hi_val + silu_f((a0 + a1) + (a2 + a3));
    s_hnew[t] = hn;
    hw[(bN + i) * F + t] = hn;
  }
  __syncthreads();

  if (PRE) {  // next-step node precomp from updated h
    if (t < 228) {
      float a0 = 0.f, a1 = 0.f, a2 = 0.f, a3 = 0.f;
      if (t < 50) { int k = t;
        #pragma unroll
        for (int r = 0; r < F; r += 4) {
          a0 += s_hnew[r] * ein_w[r * K + k];       a1 += s_hnew[r + 1] * ein_w[(r + 1) * K + k];
          a2 += s_hnew[r + 2] * ein_w[(r + 2) * K + k]; a3 += s_hnew[r + 3] * ein_w[(r + 3) * K + k];
        }
        hkA_out[(bN + i) * K + k] = (a0 + a1) + (a2 + a3);
      } else if (t < 100) { int k = t - 50;
        #pragma unroll
        for (int r = 0; r < F; r += 4) {
          a0 += s_hnew[r] * ein_w[(F + r) * K + k];       a1 += s_hnew[r + 1] * ein_w[(F + r + 1) * K + k];
          a2 += s_hnew[r + 2] * ein_w[(F + r + 2) * K + k]; a3 += s_hnew[r + 3] * ein_w[(F + r + 3) * K + k];
        }
        hkB_out[(bN + i) * K + k] = (a0 + a1) + (a2 + a3);
      } else if (t < 164) { int c = t - 100;
        #pragma unroll
        for (int r = 0; r < F; r += 4) {
          a0 += s_hnew[r] * eo1w[r * F + c];       a1 += s_hnew[r + 1] * eo1w[(r + 1) * F + c];
          a2 += s_hnew[r + 2] * eo1w[(r + 2) * F + c]; a3 += s_hnew[r + 3] * eo1w[(r + 3) * F + c];
        }
        e1A_out[(bN + i) * F + c] = (a0 + a1) + (a2 + a3);
      } else { int c = t - 164;
        #pragma unroll
        for (int r = 0; r < F; r += 4) {
          a0 += s_hnew[r] * eo1w[(F + r) * F + c];       a1 += s_hnew[r + 1] * eo1w[(F + r + 1) * F + c];
          a2 += s_hnew[r + 2] * eo1w[(F + r + 2) * F + c]; a3 += s_hnew[r + 3] * eo1w[(F + r + 3) * F + c];
        }
        e1B_out[(bN + i) * F + c] = (a0 + a1) + (a2 + a3);
      }
    }
  }
  if (TAIL) {  // coord1 halves + vel scalar m for the flow tail
    if (w == 0) {
      float a0 = 0.f, a1 = 0.f, a2 = 0.f, a3 = 0.f;
      #pragma unroll
      for (int r = 0; r < F; r += 4) {
        a0 += s_hnew[r] * c1w[r * F + lane];       a1 += s_hnew[r + 1] * c1w[(r + 1) * F + lane];
        a2 += s_hnew[r + 2] * c1w[(r + 2) * F + lane]; a3 += s_hnew[r + 3] * c1w[(r + 3) * F + lane];
      }
      uA[(bN + i) * F + lane] = (a0 + a1) + (a2 + a3);
    } else if (w == 1) {
      float a0 = 0.f, a1 = 0.f, a2 = 0.f, a3 = 0.f;
      #pragma unroll
      for (int r = 0; r < F; r += 4) {
        a0 += s_hnew[r] * c1w[(F + r) * F + lane];       a1 += s_hnew[r + 1] * c1w[(F + r + 1) * F + lane];
        a2 += s_hnew[r + 2] * c1w[(F + r + 2) * F + lane]; a3 += s_hnew[r + 3] * c1w[(F + r + 3) * F + lane];
      }
      uB[(bN + i) * F + lane] = (a0 + a1) + (a2 + a3);
    } else if (w == 2) {
      float a0 = v1b[lane], a1 = 0.f, a2 = 0.f, a3 = 0.f;
      #pragma unroll
      for (int r = 0; r < F; r += 4) {
        a0 += s_hnew[r] * v1w[r * F + lane];       a1 += s_hnew[r + 1] * v1w[(r + 1) * F + lane];
        a2 += s_hnew[r + 2] * v1w[(r + 2) * F + lane]; a3 += s_hnew[r + 3] * v1w[(r + 3) * F + lane];
      }
      float tv = silu_f((a0 + a1) + (a2 + a3)) * v2w[lane];
      #pragma unroll
      for (int off = 32; off > 0; off >>= 1) tv += __shfl_down(tv, off);
      if (lane == 0) mbuf[bN + i] = tv;
    }
  }
}

// delta_v[b,i] = (1/N) sum_j (coord2 . silu(uA_i + uB_j + b)) * (x_i - x_j)
__global__ __launch_bounds__(256) void k_tail(const float* __restrict__ xb,
    const float* __restrict__ uA, const float* __restrict__ uB,
    const float* __restrict__ c1b, const float* __restrict__ c2w,
    float* __restrict__ dv) {
  int blk = blockIdx.x, b = blk >> 7, i = blk & 127;
  int t = threadIdx.x, w = t >> 6, lane = t & 63;
  __shared__ float s_xpos[N * 3];
  __shared__ float s_uAi[F];
  __shared__ float s_acc[4][3];
  for (int idx = t; idx < N * 3; idx += 256) s_xpos[idx] = xb[b * N * 3 + idx];
  if (t < F) s_uAi[t] = uA[(b * N + i) * F + t];
  __syncthreads();
  float xi0 = s_xpos[i * 3 + 0], xi1 = s_xpos[i * 3 + 1], xi2 = s_xpos[i * 3 + 2];
  float base = s_uAi[lane] + c1b[lane];
  float c2v = c2w[lane];
  float a0 = 0.f, a1 = 0.f, a2 = 0.f;
  for (int jj = 0; jj < 32; ++jj) {
    int j = w + 4 * jj;
    float tv = silu_f(base + uB[(b * N + j) * F + lane]) * c2v;
    #pragma unroll
    for (int off = 32; off > 0; off >>= 1) tv += __shfl_down(tv, off);
    if (lane == 0) {
      float dx0 = xi0 - s_xpos[j * 3 + 0];
      float dx1 = xi1 - s_xpos[j * 3 + 1];
      float dx2 = xi2 - s_xpos[j * 3 + 2];
      a0 += tv * dx0; a1 += tv * dx1; a2 += tv * dx2;
    }
  }
  if (lane == 0) { s_acc[w][0] = a0; s_acc[w][1] = a1; s_acc[w][2] = a2; }
  __syncthreads();
  if (t < 3) {
    float s = s_acc[0][t] + s_acc[1][t] + s_acc[2][t] + s_acc[3][t];
    dv[(b * N + i) * 3 + t] = s * (1.0f / (float)N);
  }
}

// apply v' = exp(m)*v + dv, x' = x + v'; center x and v; sld += 3*sum(m). One block per batch.
__global__ __launch_bounds__(128) void k_fin(float* __restrict__ xb, float* __restrict__ vb,
    const float* __restrict__ dv, const float* __restrict__ mbuf, float* __restrict__ sld) {
  int b = blockIdx.x, t = threadIdx.x;
  __shared__ float red[N];
  float m = mbuf[b * N + t];
  float em = __expf(m);
  float vv[3], xx[3];
  #pragma unroll
  for (int d = 0; d < 3; ++d) {
    int idx = (b * N + t) * 3 + d;
    vv[d] = em * vb[idx] + dv[idx];
    xx[d] = xb[idx] + vv[d];
  }
  #pragma unroll
  for (int d = 0; d < 3; ++d) {
    red[t] = xx[d];
    __syncthreads();
    for (int s = 64; s > 0; s >>= 1) { if (t < s) red[t] += red[t + s]; __syncthreads(); }
    xx[d] -= red[0] * (1.0f / (float)N);
    __syncthreads();
    red[t] = vv[d];
    __syncthreads();
    for (int s = 64; s > 0; s >>= 1) { if (t < s) red[t] += red[t + s]; __syncthreads(); }
    vv[d] -= red[0] * (1.0f / (float)N);
    __syncthreads();
  }
  #pragma unroll
  for (int d = 0; d < 3; ++d) {
    int idx = (b * N + t) * 3 + d;
    xb[idx] = xx[d];
    vb[idx] = vv[d];
  }
  red[t] = m;
  __syncthreads();
  for (int s = 64; s > 0; s >>= 1) { if (t < s) red[t] += red[t + s]; __syncthreads(); }
  if (t == 0) sld[b] += 3.0f * red[0];
}

__global__ void k_out(const float* __restrict__ xw, const float* __restrict__ vw,
                      const float* __restrict__ sld, float* __restrict__ out) {
  int t = blockIdx.x * blockDim.x + threadIdx.x;
  if (t < B * N * 3) { out[t] = xw[t]; out[B * N * 3 + t] = vw[t]; }
  if (t < B) out[2 * B * N * 3 + t] = sld[t];
}

}  // namespace

extern "C" void kernel_launch(void* const* d_in, const int* in_sizes, int n_in,
                              void* d_out, int out_size, void* d_ws, size_t ws_size,
                              hipStream_t stream) {
  const float* in_h   = (const float*)d_in[0];
  const float* in_x   = (const float*)d_in[1];
  const float* in_v   = (const float*)d_in[2];
  const float* emb1_w = (const float*)d_in[3];
  const float* emb1_b = (const float*)d_in[4];
  const float* emb2_w = (const float*)d_in[5];
  const float* emb2_b = (const float*)d_in[6];
  const float* ein_w  = (const float*)d_in[7];
  const float* ein_b  = (const float*)d_in[8];
  const float* rbf_m  = (const float*)d_in[9];
  const float* rbf_b  = (const float*)d_in[10];
  const float* eo1w   = (const float*)d_in[11];
  const float* eo1b   = (const float*)d_in[12];
  const float* eo2w   = (const float*)d_in[13];
  const float* eo2b   = (const float*)d_in[14];
  const float* xmix   = (const float*)d_in[15];
  const float* p1w    = (const float*)d_in[16];
  const float* p1b    = (const float*)d_in[17];
  const float* p2w    = (const float*)d_in[18];
  const float* p2b    = (const float*)d_in[19];
  const float* semw   = (const float*)d_in[20];
  const float* semb   = (const float*)d_in[21];
  const float* n1w    = (const float*)d_in[22];
  const float* n1b    = (const float*)d_in[23];
  const float* n2w    = (const float*)d_in[24];
  const float* n2b    = (const float*)d_in[25];
  const float* v1w    = (const float*)d_in[26];
  const float* v1b    = (const float*)d_in[27];
  const float* v2w    = (const float*)d_in[28];
  const float* c1w    = (const float*)d_in[29];
  const float* c1b    = (const float*)d_in[30];
  const float* c2w    = (const float*)d_in[31];

  float* ws   = (float*)d_ws;
  float* h0   = ws;                 // BN*F
  float* hw   = h0 + BN * F;        // BN*F
  float* hkA0 = hw + BN * F;        // BN*K
  float* hkB0 = hkA0 + BN * K;
  float* e1A0 = hkB0 + BN * K;      // BN*F
  float* e1B0 = e1A0 + BN * F;
  float* hkA1 = e1B0 + BN * F;
  float* hkB1 = hkA1 + BN * K;
  float* e1A1 = hkB1 + BN * K;
  float* e1B1 = e1A1 + BN * F;
  float* uA   = e1B1 + BN * F;      // BN*F
  float* uB   = uA + BN * F;
  float* xw   = uB + BN * F;        // BN*3
  float* vw   = xw + BN * 3;
  float* dvb  = vw + BN * 3;
  float* mbuf = dvb + BN * 3;       // BN
  float* sld  = mbuf + BN;          // B
  float* mS   = sld + B;            // BN*2*8
  float* Up   = mS + BN * 2 * 8;    // BN*2*256
  float* cp   = Up + BN * 2 * 256;  // BN*2*768

  k_init<<<6, 256, 0, stream>>>(in_x, in_v, xw, vw, sld);
  k_embed<<<BN, F, 0, stream>>>(in_h, emb1_w, emb1_b, emb2_w, emb2_b, h0);

  float* hkA[2] = {hkA0, hkA1};
  float* hkB[2] = {hkB0, hkB1};
  float* e1A[2] = {e1A0, e1A1};
  float* e1B[2] = {e1B0, e1B1};

  for (int dep = 0; dep < 2; ++dep) {
    for (int half = 0; half < 2; ++half) {
      int l = 2 * dep + half;
      float* xb = half ? vw : xw;
      float* vb = half ? xw : vw;
      const float* einw_l = ein_w + l * 2 * F * K;
      const float* einb_l = ein_b + l * K;
      const float* rbm_l  = rbf_m + l * K;
      const float* rbb_l  = rbf_b + l * K;
      const float* eo1w_l = eo1w + l * 179 * F;
      const float* eo1b_l = eo1b + l * F;
      const float* eo2w_l = eo2w + l * F * F;
      const float* eo2b_l = eo2b + l * F;
      const float* xmix_l = xmix + l * F * C;
      const float* p1w_l  = p1w + l * C * F;
      const float* p1b_l  = p1b + l * F;
      const float* p2w_l  = p2w + l * F * F;
      const float* p2b_l  = p2b + l * F;
      const float* semw_l = semw + l * F * H;
      const float* semb_l = semb + l * H;
      const float* n1w_l  = n1w + l * 384 * F;
      const float* n1b_l  = n1b + l * F;
      const float* n2w_l  = n2w + l * F * F;
      const float* n2b_l  = n2b + l * F;
      const float* v1w_l  = v1w + l * F * F;
      const float* v1b_l  = v1b + l * F;
      const float* v2w_l  = v2w + l * F;
      const float* c1w_l  = c1w + l * 2 * F * F;
      const float* c1b_l  = c1b + l * F;
      const float* c2w_l  = c2w + l * F;

      k_pre<<<BN, 256, 0, stream>>>(h0, hw, einw_l, eo1w_l, hkA[0], hkB[0], e1A[0], e1B[0]);
      // step 0: in set0 -> out set1 ; step 1: in set1 -> out set0 ; step 2: in set0, tail
      k_edge<<<BN * 2, 256, 0, stream>>>(xb, hkA[0], hkB[0], e1A[0], e1B[0],
          einb_l, rbm_l, rbb_l, eo1w_l, eo1b_l, eo2w_l, eo2b_l, xmix_l, semw_l, semb_l,
          mS, Up, cp);
      k_comb<1, 0><<<BN, 256, 0, stream>>>(hw, mS, Up, cp,
          p1w_l, p1b_l, p2w_l, p2b_l, n1w_l, n1b_l, n2w_l, n2b_l,
          einw_l, eo1w_l, hkA[1], hkB[1], e1A[1], e1B[1],
          c1w_l, v1w_l, v1b_l, v2w_l, uA, uB, mbuf);
      k_edge<<<BN * 2, 256, 0, stream>>>(xb, hkA[1], hkB[1], e1A[1], e1B[1],
          einb_l, rbm_l, rbb_l, eo1w_l, eo1b_l, eo2w_l, eo2b_l, xmix_l, semw_l, semb_l,
          mS, Up, cp);
      k_comb<1, 0><<<BN, 256, 0, stream>>>(hw, mS, Up, cp,
          p1w_l, p1b_l, p2w_l, p2b_l, n1w_l, n1b_l, n2w_l, n2b_l,
          einw_l, eo1w_l, hkA[0], hkB[0], e1A[0], e1B[0],
          c1w_l, v1w_l, v1b_l, v2w_l, uA, uB, mbuf);
      k_edge<<<BN * 2, 256, 0, stream>>>(xb, hkA[0], hkB[0], e1A[0], e1B[0],
          einb_l, rbm_l, rbb_l, eo1w_l, eo1b_l, eo2w_l, eo2b_l, xmix_l, semw_l, semb_l,
          mS, Up, cp);
      k_comb<0, 1><<<BN, 256, 0, stream>>>(hw, mS, Up, cp,
          p1w_l, p1b_l, p2w_l, p2b_l, n1w_l, n1b_l, n2w_l, n2b_l,
          einw_l, eo1w_l, hkA[1], hkB[1], e1A[1], e1B[1],
          c1w_l, v1w_l, v1b_l, v2w_l, uA, uB, mbuf);
      k_tail<<<BN, 256, 0, stream>>>(xb, uA, uB, c1b_l, c2w_l, dvb);
      k_fin<<<B, 128, 0, stream>>>(xb, vb, dvb, mbuf, sld);
    }
  }
  k_out<<<6, 256, 0, stream>>>(xw, vw, sld, (float*)d_out);
}

// Round 8
// 1097.940 us; speedup vs baseline: 3.6080x; 2.3039x over previous
//
#include <hip/hip_runtime.h>
#include <math.h>

namespace {

constexpr int B = 4, N = 128, FIN = 16, F = 64, H = 4, K = 50, C = 256;
constexpr int BN = B * N;
constexpr float EPS = 1e-5f;

__device__ __forceinline__ float silu_f(float x) { return x / (1.0f + __expf(-x)); }
__device__ __forceinline__ float tanh_f(float x) { return 1.0f - 2.0f / (__expf(2.0f * x) + 1.0f); }

__global__ void k_init(const float* __restrict__ x, const float* __restrict__ v,
                       float* __restrict__ xw, float* __restrict__ vw, float* __restrict__ sld) {
  int t = blockIdx.x * blockDim.x + threadIdx.x;
  if (t < B * N * 3) { xw[t] = x[t]; vw[t] = v[t]; }
  if (t < B) sld[t] = 0.0f;
}

__global__ __launch_bounds__(F) void k_embed(const float* __restrict__ hin,
    const float* __restrict__ w1, const float* __restrict__ b1,
    const float* __restrict__ w2, const float* __restrict__ b2, float* __restrict__ h0) {
  int node = blockIdx.x, f = threadIdx.x;
  __shared__ float t1[F];
  float acc = b1[f];
  #pragma unroll
  for (int r = 0; r < FIN; ++r) acc += hin[node * FIN + r] * w1[r * F + f];
  t1[f] = silu_f(acc);
  __syncthreads();
  float a0 = b2[f], a1 = 0.f, a2 = 0.f, a3 = 0.f;
  #pragma unroll
  for (int r = 0; r < F; r += 4) {
    a0 += t1[r] * w2[r * F + f];
    a1 += t1[r + 1] * w2[(r + 1) * F + f];
    a2 += t1[r + 2] * w2[(r + 2) * F + f];
    a3 += t1[r + 3] * w2[(r + 3) * F + f];
  }
  h0[node * F + f] = (a0 + a1) + (a2 + a3);
}

// Per-node precomputation at flow start: hkA/hkB (edge_in halves), e1A/e1B (eo1 halves).
__global__ __launch_bounds__(256) void k_pre(const float* __restrict__ h0, float* __restrict__ hw,
    const float* __restrict__ ein_w, const float* __restrict__ eo1w,
    float* __restrict__ hkA, float* __restrict__ hkB,
    float* __restrict__ e1A, float* __restrict__ e1B) {
  int node = blockIdx.x, t = threadIdx.x;
  __shared__ float s_h[F];
  if (t < F) s_h[t] = h0[node * F + t];
  __syncthreads();
  if (t < F) hw[node * F + t] = s_h[t];
  if (t < 228) {
    float a0 = 0.f, a1 = 0.f, a2 = 0.f, a3 = 0.f;
    if (t < 50) { int k = t;
      #pragma unroll
      for (int r = 0; r < F; r += 4) {
        a0 += s_h[r] * ein_w[r * K + k];       a1 += s_h[r + 1] * ein_w[(r + 1) * K + k];
        a2 += s_h[r + 2] * ein_w[(r + 2) * K + k]; a3 += s_h[r + 3] * ein_w[(r + 3) * K + k];
      }
      hkA[node * K + k] = (a0 + a1) + (a2 + a3);
    } else if (t < 100) { int k = t - 50;
      #pragma unroll
      for (int r = 0; r < F; r += 4) {
        a0 += s_h[r] * ein_w[(F + r) * K + k];       a1 += s_h[r + 1] * ein_w[(F + r + 1) * K + k];
        a2 += s_h[r + 2] * ein_w[(F + r + 2) * K + k]; a3 += s_h[r + 3] * ein_w[(F + r + 3) * K + k];
      }
      hkB[node * K + k] = (a0 + a1) + (a2 + a3);
    } else if (t < 164) { int c = t - 100;
      #pragma unroll
      for (int r = 0; r < F; r += 4) {
        a0 += s_h[r] * eo1w[r * F + c];       a1 += s_h[r + 1] * eo1w[(r + 1) * F + c];
        a2 += s_h[r + 2] * eo1w[(r + 2) * F + c]; a3 += s_h[r + 3] * eo1w[(r + 3) * F + c];
      }
      e1A[node * F + c] = (a0 + a1) + (a2 + a3);
    } else { int c = t - 164;
      #pragma unroll
      for (int r = 0; r < F; r += 4) {
        a0 += s_h[r] * eo1w[(F + r) * F + c];       a1 += s_h[r + 1] * eo1w[(F + r + 1) * F + c];
        a2 += s_h[r + 2] * eo1w[(F + r + 2) * F + c]; a3 += s_h[r + 3] * eo1w[(F + r + 3) * F + c];
      }
      e1B[node * F + c] = (a0 + a1) + (a2 + a3);
    }
  }
}

// Heavy half-step kernel: one block per (b, i, j-half). 256 threads / 4 waves.
// Grid = BN*2 = 1024 blocks. __launch_bounds__(256,2) keeps the proven 128-VGPR
// allocation (requesting 4 waves/EU clamps to 64 VGPR and spills -- rounds 1/6/7);
// at 128 VGPR and 39.4KB LDS the HW can still resident 4 blocks/CU = 16 waves/CU.
__global__ __launch_bounds__(256, 2) void k_edge(
    const float* __restrict__ xp,
    const float* __restrict__ hkA_in, const float* __restrict__ hkB_in,
    const float* __restrict__ e1A_in, const float* __restrict__ e1B_in,
    const float* __restrict__ ein_b, const float* __restrict__ rbf_m, const float* __restrict__ rbf_b,
    const float* __restrict__ eo1w, const float* __restrict__ eo1b,
    const float* __restrict__ eo2w, const float* __restrict__ eo2b,
    const float* __restrict__ xmix,
    const float* __restrict__ semw, const float* __restrict__ semb,
    float* __restrict__ mS, float* __restrict__ Upart, float* __restrict__ combpart) {
  int blk = blockIdx.x;
  int b = blk >> 8, i = (blk >> 1) & 127, jh = blk & 1;
  int t = threadIdx.x, w = t >> 6, lane = t & 63;
  int bN = b * N;
  int bi2 = ((bN + i) << 1) + jh;

  __shared__ __align__(16) float s_heT[64 * 68];   // he transposed [r][j_local], pad 68
  __shared__ __align__(16) float s_union[4352];    // t1buf (edge) / {cpart, att}
  __shared__ __align__(16) float4 s_dxn[64];       // (dx0,dx1,dx2,dn) for local j
  __shared__ float s_inv[64];
  __shared__ float s_xpos[N * 3];
  __shared__ float s_zkbase[K];
  __shared__ float s_e1base[F];
  __shared__ __align__(16) float s_zk[4][56];

  float* t1buf   = s_union;          // [64][68] during edge
  float* s_cpart = s_union;          // [4][256][3] = 3072 after edge
  float* s_att   = s_union + 3072;   // [4][64] unnormalized e

  // ---- staging ----
  for (int idx = t; idx < N * 3; idx += 256) s_xpos[idx] = xp[bN * 3 + idx];
  if (t < K) s_zkbase[t] = hkA_in[(bN + i) * K + t] + ein_b[t];
  if (t >= 64 && t < 128) s_e1base[t - 64] = e1A_in[(bN + i) * F + (t - 64)] + eo1b[t - 64];
  if (lane >= 50 && lane < 56) s_zk[w][lane] = 0.f;  // float4 pad
  __syncthreads();
  if (t < 64) {
    int jg = jh * 64 + t;
    float dx0 = s_xpos[i * 3 + 0] - s_xpos[jg * 3 + 0];
    float dx1 = s_xpos[i * 3 + 1] - s_xpos[jg * 3 + 1];
    float dx2 = s_xpos[i * 3 + 2] - s_xpos[jg * 3 + 2];
    float dn = sqrtf(dx0 * dx0 + dx1 * dx1 + dx2 * dx2 + EPS * EPS);
    s_dxn[t] = make_float4(dx0, dx1, dx2, dn);
    s_inv[t] = 1.0f / (dn + EPS);
  }
  __syncthreads();

  float rbm = 0.f, rbb = 0.f;
  if (lane < K) { rbm = rbf_m[lane]; rbb = rbf_b[lane]; }

  // ---- edge phase: wave w owns local j in [w*16, w*16+16) ----
  {
    int jbl = w * 16;               // local base
    int jbg = jh * 64 + jbl;        // global base
    {  // sub-pass A: t1 rows (only wk live)
      float wk[52];
      #pragma unroll
      for (int k = 0; k < 50; ++k) wk[k] = eo1w[(128 + k) * F + lane];
      wk[50] = 0.f; wk[51] = 0.f;
      float w1d = eo1w[178 * F + lane];
      float nhk = (lane < K) ? hkB_in[(bN + jbg) * K + lane] : 0.f;
      float ne1 = e1B_in[(bN + jbg) * F + lane];
      for (int jj = 0; jj < 16; ++jj) {
        int jl = jbl + jj;
        float hk = nhk, e1v = ne1;
        if (jj < 15) {
          nhk = (lane < K) ? hkB_in[(bN + jbg + jj + 1) * K + lane] : 0.f;
          ne1 = e1B_in[(bN + jbg + jj + 1) * F + lane];
        }
        float dn = s_dxn[jl].w;
        if (lane < K) {
          float hkf = s_zkbase[lane] + hk;
          float e = __expf(-dn) - rbm;
          s_zk[w][lane] = __expf(-rbb * e * e) * hkf;
        }
        float ac0 = s_e1base[lane] + e1v + dn * w1d, ac1 = 0.f, ac2 = 0.f, ac3 = 0.f;
        const float4* z4 = (const float4*)(&s_zk[w][0]);
        #pragma unroll
        for (int k4 = 0; k4 < 13; ++k4) {
          float4 z = z4[k4];
          ac0 += z.x * wk[4 * k4];     ac1 += z.y * wk[4 * k4 + 1];
          ac2 += z.z * wk[4 * k4 + 2]; ac3 += z.w * wk[4 * k4 + 3];
        }
        t1buf[jl * 68 + lane] = silu_f((ac0 + ac1) + (ac2 + ac3));
      }
    }
    // same-wave rows -> no barrier needed
    {  // sub-pass B: he = t1 @ eo2 (only er live), b128-packed writes into he_T
      float er[64];
      #pragma unroll
      for (int r = 0; r < F; ++r) er[r] = eo2w[r * F + lane];
      float b2 = eo2b[lane];
      for (int jj4 = 0; jj4 < 4; ++jj4) {
        float hv[4];
        #pragma unroll
        for (int q = 0; q < 4; ++q) {
          const float4* t4 = (const float4*)(&t1buf[(jbl + jj4 * 4 + q) * 68]);
          float ac0 = b2, ac1 = 0.f, ac2 = 0.f, ac3 = 0.f;
          #pragma unroll
          for (int r4 = 0; r4 < 16; ++r4) {
            float4 tt = t4[r4];
            ac0 += tt.x * er[4 * r4];     ac1 += tt.y * er[4 * r4 + 1];
            ac2 += tt.z * er[4 * r4 + 2]; ac3 += tt.w * er[4 * r4 + 3];
          }
          hv[q] = (ac0 + ac1) + (ac2 + ac3);
        }
        *(float4*)(&s_heT[lane * 68 + jbl + jj4 * 4]) = make_float4(hv[0], hv[1], hv[2], hv[3]);
      }
    }
  }
  __syncthreads();  // he_T complete; t1buf dead -> union becomes cpart/att

  // ---- coeff partial: register-tiled 8j x 4c, 2 passes over this wave's 16 j ----
  {
    int c0 = 4 * (t & 63);
    float4 aX = make_float4(0.f, 0.f, 0.f, 0.f);
    float4 aY = make_float4(0.f, 0.f, 0.f, 0.f);
    float4 aZ = make_float4(0.f, 0.f, 0.f, 0.f);
    #pragma unroll 1
    for (int p = 0; p < 2; ++p) {
      int j0 = w * 16 + p * 8;   // local j
      float4 cacc[8];
      #pragma unroll
      for (int jj = 0; jj < 8; ++jj) cacc[jj] = make_float4(0.f, 0.f, 0.f, 0.f);
      for (int r = 0; r < 64; ++r) {
        float4 xm4 = *(const float4*)(&xmix[r * C + c0]);
        const float4* hb = (const float4*)(&s_heT[r * 68 + j0]);
        float4 h0v = hb[0], h1v = hb[1];
#define CSTEP(idx, hval) \
        cacc[idx].x += (hval) * xm4.x; cacc[idx].y += (hval) * xm4.y; \
        cacc[idx].z += (hval) * xm4.z; cacc[idx].w += (hval) * xm4.w;
        CSTEP(0, h0v.x)  CSTEP(1, h0v.y)  CSTEP(2, h0v.z)  CSTEP(3, h0v.w)
        CSTEP(4, h1v.x)  CSTEP(5, h1v.y)  CSTEP(6, h1v.z)  CSTEP(7, h1v.w)
#undef CSTEP
      }
      #pragma unroll
      for (int jj = 0; jj < 8; ++jj) {
        int jl = j0 + jj;
        float4 dq = s_dxn[jl];
        float inv = s_inv[jl];
        float s0 = tanh_f(cacc[jj].x) * inv;
        float s1 = tanh_f(cacc[jj].y) * inv;
        float s2 = tanh_f(cacc[jj].z) * inv;
        float s3 = tanh_f(cacc[jj].w) * inv;
        aX.x += dq.x * s0; aY.x += dq.y * s0; aZ.x += dq.z * s0;
        aX.y += dq.x * s1; aY.y += dq.y * s1; aZ.y += dq.z * s1;
        aX.z += dq.x * s2; aY.z += dq.y * s2; aZ.z += dq.z * s2;
        aX.w += dq.x * s3; aY.w += dq.y * s3; aZ.w += dq.z * s3;
      }
    }
    int cb = w * 768 + c0 * 3;
    s_cpart[cb + 0] = aX.x; s_cpart[cb + 1] = aY.x; s_cpart[cb + 2]  = aZ.x;
    s_cpart[cb + 3] = aX.y; s_cpart[cb + 4] = aY.y; s_cpart[cb + 5]  = aZ.y;
    s_cpart[cb + 6] = aX.z; s_cpart[cb + 7] = aY.z; s_cpart[cb + 8]  = aZ.z;
    s_cpart[cb + 9] = aX.w; s_cpart[cb + 10] = aY.w; s_cpart[cb + 11] = aZ.w;
  }
  __syncthreads();

  // ---- combine the 4 wave partials of comb -> global ----
  {
    int c = t;
    float q0 = s_cpart[c * 3 + 0] + s_cpart[768 + c * 3 + 0] + s_cpart[1536 + c * 3 + 0] + s_cpart[2304 + c * 3 + 0];
    float q1 = s_cpart[c * 3 + 1] + s_cpart[768 + c * 3 + 1] + s_cpart[1536 + c * 3 + 1] + s_cpart[2304 + c * 3 + 1];
    float q2 = s_cpart[c * 3 + 2] + s_cpart[768 + c * 3 + 2] + s_cpart[1536 + c * 3 + 2] + s_cpart[2304 + c * 3 + 2];
    combpart[bi2 * 768 + c * 3 + 0] = q0;
    combpart[bi2 * 768 + c * 3 + 1] = q1;
    combpart[bi2 * 768 + c * 3 + 2] = q2;
  }

  // ---- logits: thread t -> (j_local = t&63, head = t>>6 = w); column reads ----
  {
    int jl = t & 63, hh = w;
    int jg = jh * 64 + jl;
    float l0a = 0.f, l0b = 0.f;
    #pragma unroll 8
    for (int r = 0; r < 64; r += 2) {
      float hv0 = s_heT[r * 68 + jl];
      float hv1 = s_heT[(r + 1) * 68 + jl];
      l0a += hv0 * semw[r * H + hh];
      l0b += hv1 * semw[(r + 1) * H + hh];
    }
    float lg = semb[hh] + l0a + l0b;
    lg = lg > 0.f ? lg : 2.0f * (__expf(0.5f * lg) - 1.0f);  // celu alpha=2
    if (jg == i) lg -= 1e5f;
    float m = lg;
    #pragma unroll
    for (int off = 32; off > 0; off >>= 1) m = fmaxf(m, __shfl_xor(m, off));
    float e = __expf(lg - m);
    float S = e;
    #pragma unroll
    for (int off = 32; off > 0; off >>= 1) S += __shfl_xor(S, off);
    s_att[hh * 64 + jl] = e;
    if (lane == 0) { mS[bi2 * 8 + hh * 2] = m; mS[bi2 * 8 + hh * 2 + 1] = S; }
  }
  __syncthreads();

  // ---- U partial: thread t -> (f = t>>2, head = t&3); j-contiguous b128 reads ----
  {
    int f = t >> 2, hh = t & 3;
    const float4* hr = (const float4*)(&s_heT[f * 68]);
    const float4* ar = (const float4*)(&s_att[hh * 64]);
    float ac0 = 0.f, ac1 = 0.f, ac2 = 0.f, ac3 = 0.f;
    #pragma unroll 8
    for (int jg4 = 0; jg4 < 16; ++jg4) {
      float4 hv = hr[jg4];
      float4 av = ar[jg4];
      ac0 += hv.x * av.x; ac1 += hv.y * av.y; ac2 += hv.z * av.z; ac3 += hv.w * av.w;
    }
    Upart[bi2 * 256 + t] = (ac0 + ac1) + (ac2 + ac3);
  }
}

// Light combine kernel: one block per (b,i). Rescale-combine softmax halves,
// hcin, node MLPs + residual, plus PRE (next-step precomp) or TAIL outputs.
template<int PRE, int TAIL>
__global__ __launch_bounds__(256, 2) void k_comb(
    float* __restrict__ hw,
    const float* __restrict__ mS, const float* __restrict__ Upart, const float* __restrict__ combpart,
    const float* __restrict__ p1w, const float* __restrict__ p1b,
    const float* __restrict__ p2w, const float* __restrict__ p2b,
    const float* __restrict__ n1w, const float* __restrict__ n1b,
    const float* __restrict__ n2w, const float* __restrict__ n2b,
    const float* __restrict__ ein_w, const float* __restrict__ eo1w,
    float* __restrict__ hkA_out, float* __restrict__ hkB_out,
    float* __restrict__ e1A_out, float* __restrict__ e1B_out,
    const float* __restrict__ c1w, const float* __restrict__ v1w, const float* __restrict__ v1b,
    const float* __restrict__ v2w,
    float* __restrict__ uA, float* __restrict__ uB, float* __restrict__ mbuf) {
  int blk = blockIdx.x, b = blk >> 7, i = blk & 127;
  int t = threadIdx.x, w = t >> 6, lane = t & 63;
  int bN = b * N;
  int bi2 = (bN + i) << 1;
  constexpr float invN = 1.0f / (float)N;

  __shared__ float s_hcin[C];
  __shared__ float s_cat[384];
  __shared__ float s_part[4][F];
  __shared__ float s_vec[F];
  __shared__ float s_hnew[F];

  float hi_val = (t < F) ? hw[(bN + i) * F + t] : 0.f;

  // ---- h_e combine (flash-style rescale) ----
  {
    int hh = t & 3;
    float m0 = mS[bi2 * 8 + hh * 2],       S0 = mS[bi2 * 8 + hh * 2 + 1];
    float m1 = mS[(bi2 + 1) * 8 + hh * 2], S1 = mS[(bi2 + 1) * 8 + hh * 2 + 1];
    float m = fmaxf(m0, m1);
    float w0 = __expf(m0 - m), w1 = __expf(m1 - m);
    float u = w0 * Upart[bi2 * 256 + t] + w1 * Upart[(bi2 + 1) * 256 + t];
    s_cat[64 + t] = u / (w0 * S0 + w1 * S1);
  }
  // ---- hcin combine ----
  {
    int c = t;
    float q0 = (combpart[bi2 * 768 + c * 3 + 0] + combpart[(bi2 + 1) * 768 + c * 3 + 0]) * invN;
    float q1 = (combpart[bi2 * 768 + c * 3 + 1] + combpart[(bi2 + 1) * 768 + c * 3 + 1]) * invN;
    float q2 = (combpart[bi2 * 768 + c * 3 + 2] + combpart[(bi2 + 1) * 768 + c * 3 + 2]) * invN;
    s_hcin[c] = q0 * q0 + q1 * q1 + q2 * q2;
  }
  __syncthreads();

  // ---- node phase (proven 256-thread version) ----
  {
    int c0 = w * 64;
    float a0 = 0.f, a1 = 0.f, a2 = 0.f, a3 = 0.f;
    #pragma unroll 8
    for (int cc = 0; cc < 64; cc += 4) {
      a0 += s_hcin[c0 + cc] * p1w[(c0 + cc) * F + lane];
      a1 += s_hcin[c0 + cc + 1] * p1w[(c0 + cc + 1) * F + lane];
      a2 += s_hcin[c0 + cc + 2] * p1w[(c0 + cc + 2) * F + lane];
      a3 += s_hcin[c0 + cc + 3] * p1w[(c0 + cc + 3) * F + lane];
    }
    s_part[w][lane] = (a0 + a1) + (a2 + a3);
  }
  __syncthreads();
  if (t < F) s_vec[t] = silu_f(s_part[0][t] + s_part[1][t] + s_part[2][t] + s_part[3][t] + p1b[t]);
  __syncthreads();
  if (t < F) {
    float a0 = p2b[t], a1 = 0.f, a2 = 0.f, a3 = 0.f;
    #pragma unroll 8
    for (int r = 0; r < F; r += 4) {
      a0 += s_vec[r] * p2w[r * F + t];
      a1 += s_vec[r + 1] * p2w[(r + 1) * F + t];
      a2 += s_vec[r + 2] * p2w[(r + 2) * F + t];
      a3 += s_vec[r + 3] * p2w[(r + 3) * F + t];
    }
    s_cat[t] = hi_val;
    s_cat[320 + t] = silu_f((a0 + a1) + (a2 + a3));
  }
  __syncthreads();
  {
    int r0 = w * 96;
    float a0 = 0.f, a1 = 0.f, a2 = 0.f, a3 = 0.f;
    #pragma unroll 8
    for (int rr = 0; rr < 96; rr += 4) {
      a0 += s_cat[r0 + rr] * n1w[(r0 + rr) * F + lane];
      a1 += s_cat[r0 + rr + 1] * n1w[(r0 + rr + 1) * F + lane];
      a2 += s_cat[r0 + rr + 2] * n1w[(r0 + rr + 2) * F + lane];
      a3 += s_cat[r0 + rr + 3] * n1w[(r0 + rr + 3) * F + lane];
    }
    s_part[w][lane] = (a0 + a1) + (a2 + a3);
  }
  __syncthreads();
  if (t < F) s_vec[t] = silu_f(s_part[0][t] + s_part[1][t] + s_part[2][t] + s_part[3][t] + n1b[t]);
  __syncthreads();
  if (t < F) {
    float a0 = n2b[t], a1 = 0.f, a2 = 0.f, a3 = 0.f;
    #pragma unroll 8
    for (int r = 0; r < F; r += 4) {
      a0 += s_vec[r] * n2w[r * F + t];
      a1 += s_vec[r + 1] * n2w[(r + 1) * F + t];
      a2 += s_vec[r + 2] * n2w[(r + 2) * F + t];
      a3 += s_vec[r + 3] * n2w[(r + 3) * F + t];
    }
    float hn = hi_val + silu_f((a0 + a1) + (a2 + a3));
    s_hnew[t] = hn;
    hw[(bN + i) * F + t] = hn;
  }
  __syncthreads();

  if (PRE) {  // next-step node precomp from updated h
    if (t < 228) {
      float a0 = 0.f, a1 = 0.f, a2 = 0.f, a3 = 0.f;
      if (t < 50) { int k = t;
        #pragma unroll
        for (int r = 0; r < F; r += 4) {
          a0 += s_hnew[r] * ein_w[r * K + k];       a1 += s_hnew[r + 1] * ein_w[(r + 1) * K + k];
          a2 += s_hnew[r + 2] * ein_w[(r + 2) * K + k]; a3 += s_hnew[r + 3] * ein_w[(r + 3) * K + k];
        }
        hkA_out[(bN + i) * K + k] = (a0 + a1) + (a2 + a3);
      } else if (t < 100) { int k = t - 50;
        #pragma unroll
        for (int r = 0; r < F; r += 4) {
          a0 += s_hnew[r] * ein_w[(F + r) * K + k];       a1 += s_hnew[r + 1] * ein_w[(F + r + 1) * K + k];
          a2 += s_hnew[r + 2] * ein_w[(F + r + 2) * K + k]; a3 += s_hnew[r + 3] * ein_w[(F + r + 3) * K + k];
        }
        hkB_out[(bN + i) * K + k] = (a0 + a1) + (a2 + a3);
      } else if (t < 164) { int c = t - 100;
        #pragma unroll
        for (int r = 0; r < F; r += 4) {
          a0 += s_hnew[r] * eo1w[r * F + c];       a1 += s_hnew[r + 1] * eo1w[(r + 1) * F + c];
          a2 += s_hnew[r + 2] * eo1w[(r + 2) * F + c]; a3 += s_hnew[r + 3] * eo1w[(r + 3) * F + c];
        }
        e1A_out[(bN + i) * F + c] = (a0 + a1) + (a2 + a3);
      } else { int c = t - 164;
        #pragma unroll
        for (int r = 0; r < F; r += 4) {
          a0 += s_hnew[r] * eo1w[(F + r) * F + c];       a1 += s_hnew[r + 1] * eo1w[(F + r + 1) * F + c];
          a2 += s_hnew[r + 2] * eo1w[(F + r + 2) * F + c]; a3 += s_hnew[r + 3] * eo1w[(F + r + 3) * F + c];
        }
        e1B_out[(bN + i) * F + c] = (a0 + a1) + (a2 + a3);
      }
    }
  }
  if (TAIL) {  // coord1 halves + vel scalar m for the flow tail
    if (w == 0) {
      float a0 = 0.f, a1 = 0.f, a2 = 0.f, a3 = 0.f;
      #pragma unroll
      for (int r = 0; r < F; r += 4) {
        a0 += s_hnew[r] * c1w[r * F + lane];       a1 += s_hnew[r + 1] * c1w[(r + 1) * F + lane];
        a2 += s_hnew[r + 2] * c1w[(r + 2) * F + lane]; a3 += s_hnew[r + 3] * c1w[(r + 3) * F + lane];
      }
      uA[(bN + i) * F + lane] = (a0 + a1) + (a2 + a3);
    } else if (w == 1) {
      float a0 = 0.f, a1 = 0.f, a2 = 0.f, a3 = 0.f;
      #pragma unroll
      for (int r = 0; r < F; r += 4) {
        a0 += s_hnew[r] * c1w[(F + r) * F + lane];       a1 += s_hnew[r + 1] * c1w[(F + r + 1) * F + lane];
        a2 += s_hnew[r + 2] * c1w[(F + r + 2) * F + lane]; a3 += s_hnew[r + 3] * c1w[(F + r + 3) * F + lane];
      }
      uB[(bN + i) * F + lane] = (a0 + a1) + (a2 + a3);
    } else if (w == 2) {
      float a0 = v1b[lane], a1 = 0.f, a2 = 0.f, a3 = 0.f;
      #pragma unroll
      for (int r = 0; r < F; r += 4) {
        a0 += s_hnew[r] * v1w[r * F + lane];       a1 += s_hnew[r + 1] * v1w[(r + 1) * F + lane];
        a2 += s_hnew[r + 2] * v1w[(r + 2) * F + lane]; a3 += s_hnew[r + 3] * v1w[(r + 3) * F + lane];
      }
      float tv = silu_f((a0 + a1) + (a2 + a3)) * v2w[lane];
      #pragma unroll
      for (int off = 32; off > 0; off >>= 1) tv += __shfl_down(tv, off);
      if (lane == 0) mbuf[bN + i] = tv;
    }
  }
}

// delta_v[b,i] = (1/N) sum_j (coord2 . silu(uA_i + uB_j + b)) * (x_i - x_j)
__global__ __launch_bounds__(256) void k_tail(const float* __restrict__ xb,
    const float* __restrict__ uA, const float* __restrict__ uB,
    const float* __restrict__ c1b, const float* __restrict__ c2w,
    float* __restrict__ dv) {
  int blk = blockIdx.x, b = blk >> 7, i = blk & 127;
  int t = threadIdx.x, w = t >> 6, lane = t & 63;
  __shared__ float s_xpos[N * 3];
  __shared__ float s_uAi[F];
  __shared__ float s_acc[4][3];
  for (int idx = t; idx < N * 3; idx += 256) s_xpos[idx] = xb[b * N * 3 + idx];
  if (t < F) s_uAi[t] = uA[(b * N + i) * F + t];
  __syncthreads();
  float xi0 = s_xpos[i * 3 + 0], xi1 = s_xpos[i * 3 + 1], xi2 = s_xpos[i * 3 + 2];
  float base = s_uAi[lane] + c1b[lane];
  float c2v = c2w[lane];
  float a0 = 0.f, a1 = 0.f, a2 = 0.f;
  for (int jj = 0; jj < 32; ++jj) {
    int j = w + 4 * jj;
    float tv = silu_f(base + uB[(b * N + j) * F + lane]) * c2v;
    #pragma unroll
    for (int off = 32; off > 0; off >>= 1) tv += __shfl_down(tv, off);
    if (lane == 0) {
      float dx0 = xi0 - s_xpos[j * 3 + 0];
      float dx1 = xi1 - s_xpos[j * 3 + 1];
      float dx2 = xi2 - s_xpos[j * 3 + 2];
      a0 += tv * dx0; a1 += tv * dx1; a2 += tv * dx2;
    }
  }
  if (lane == 0) { s_acc[w][0] = a0; s_acc[w][1] = a1; s_acc[w][2] = a2; }
  __syncthreads();
  if (t < 3) {
    float s = s_acc[0][t] + s_acc[1][t] + s_acc[2][t] + s_acc[3][t];
    dv[(b * N + i) * 3 + t] = s * (1.0f / (float)N);
  }
}

// apply v' = exp(m)*v + dv, x' = x + v'; center x and v; sld += 3*sum(m). One block per batch.
__global__ __launch_bounds__(128) void k_fin(float* __restrict__ xb, float* __restrict__ vb,
    const float* __restrict__ dv, const float* __restrict__ mbuf, float* __restrict__ sld) {
  int b = blockIdx.x, t = threadIdx.x;
  __shared__ float red[N];
  float m = mbuf[b * N + t];
  float em = __expf(m);
  float vv[3], xx[3];
  #pragma unroll
  for (int d = 0; d < 3; ++d) {
    int idx = (b * N + t) * 3 + d;
    vv[d] = em * vb[idx] + dv[idx];
    xx[d] = xb[idx] + vv[d];
  }
  #pragma unroll
  for (int d = 0; d < 3; ++d) {
    red[t] = xx[d];
    __syncthreads();
    for (int s = 64; s > 0; s >>= 1) { if (t < s) red[t] += red[t + s]; __syncthreads(); }
    xx[d] -= red[0] * (1.0f / (float)N);
    __syncthreads();
    red[t] = vv[d];
    __syncthreads();
    for (int s = 64; s > 0; s >>= 1) { if (t < s) red[t] += red[t + s]; __syncthreads(); }
    vv[d] -= red[0] * (1.0f / (float)N);
    __syncthreads();
  }
  #pragma unroll
  for (int d = 0; d < 3; ++d) {
    int idx = (b * N + t) * 3 + d;
    xb[idx] = xx[d];
    vb[idx] = vv[d];
  }
  red[t] = m;
  __syncthreads();
  for (int s = 64; s > 0; s >>= 1) { if (t < s) red[t] += red[t + s]; __syncthreads(); }
  if (t == 0) sld[b] += 3.0f * red[0];
}

__global__ void k_out(const float* __restrict__ xw, const float* __restrict__ vw,
                      const float* __restrict__ sld, float* __restrict__ out) {
  int t = blockIdx.x * blockDim.x + threadIdx.x;
  if (t < B * N * 3) { out[t] = xw[t]; out[B * N * 3 + t] = vw[t]; }
  if (t < B) out[2 * B * N * 3 + t] = sld[t];
}

}  // namespace

extern "C" void kernel_launch(void* const* d_in, const int* in_sizes, int n_in,
                              void* d_out, int out_size, void* d_ws, size_t ws_size,
                              hipStream_t stream) {
  const float* in_h   = (const float*)d_in[0];
  const float* in_x   = (const float*)d_in[1];
  const float* in_v   = (const float*)d_in[2];
  const float* emb1_w = (const float*)d_in[3];
  const float* emb1_b = (const float*)d_in[4];
  const float* emb2_w = (const float*)d_in[5];
  const float* emb2_b = (const float*)d_in[6];
  const float* ein_w  = (const float*)d_in[7];
  const float* ein_b  = (const float*)d_in[8];
  const float* rbf_m  = (const float*)d_in[9];
  const float* rbf_b  = (const float*)d_in[10];
  const float* eo1w   = (const float*)d_in[11];
  const float* eo1b   = (const float*)d_in[12];
  const float* eo2w   = (const float*)d_in[13];
  const float* eo2b   = (const float*)d_in[14];
  const float* xmix   = (const float*)d_in[15];
  const float* p1w    = (const float*)d_in[16];
  const float* p1b    = (const float*)d_in[17];
  const float* p2w    = (const float*)d_in[18];
  const float* p2b    = (const float*)d_in[19];
  const float* semw   = (const float*)d_in[20];
  const float* semb   = (const float*)d_in[21];
  const float* n1w    = (const float*)d_in[22];
  const float* n1b    = (const float*)d_in[23];
  const float* n2w    = (const float*)d_in[24];
  const float* n2b    = (const float*)d_in[25];
  const float* v1w    = (const float*)d_in[26];
  const float* v1b    = (const float*)d_in[27];
  const float* v2w    = (const float*)d_in[28];
  const float* c1w    = (const float*)d_in[29];
  const float* c1b    = (const float*)d_in[30];
  const float* c2w    = (const float*)d_in[31];

  float* ws   = (float*)d_ws;
  float* h0   = ws;                 // BN*F
  float* hw   = h0 + BN * F;        // BN*F
  float* hkA0 = hw + BN * F;        // BN*K
  float* hkB0 = hkA0 + BN * K;
  float* e1A0 = hkB0 + BN * K;      // BN*F
  float* e1B0 = e1A0 + BN * F;
  float* hkA1 = e1B0 + BN * F;
  float* hkB1 = hkA1 + BN * K;
  float* e1A1 = hkB1 + BN * K;
  float* e1B1 = e1A1 + BN * F;
  float* uA   = e1B1 + BN * F;      // BN*F
  float* uB   = uA + BN * F;
  float* xw   = uB + BN * F;        // BN*3
  float* vw   = xw + BN * 3;
  float* dvb  = vw + BN * 3;
  float* mbuf = dvb + BN * 3;       // BN
  float* sld  = mbuf + BN;          // B
  float* mS   = sld + B;            // BN*2*8
  float* Up   = mS + BN * 2 * 8;    // BN*2*256
  float* cp   = Up + BN * 2 * 256;  // BN*2*768

  k_init<<<6, 256, 0, stream>>>(in_x, in_v, xw, vw, sld);
  k_embed<<<BN, F, 0, stream>>>(in_h, emb1_w, emb1_b, emb2_w, emb2_b, h0);

  float* hkA[2] = {hkA0, hkA1};
  float* hkB[2] = {hkB0, hkB1};
  float* e1A[2] = {e1A0, e1A1};
  float* e1B[2] = {e1B0, e1B1};

  for (int dep = 0; dep < 2; ++dep) {
    for (int half = 0; half < 2; ++half) {
      int l = 2 * dep + half;
      float* xb = half ? vw : xw;
      float* vb = half ? xw : vw;
      const float* einw_l = ein_w + l * 2 * F * K;
      const float* einb_l = ein_b + l * K;
      const float* rbm_l  = rbf_m + l * K;
      const float* rbb_l  = rbf_b + l * K;
      const float* eo1w_l = eo1w + l * 179 * F;
      const float* eo1b_l = eo1b + l * F;
      const float* eo2w_l = eo2w + l * F * F;
      const float* eo2b_l = eo2b + l * F;
      const float* xmix_l = xmix + l * F * C;
      const float* p1w_l  = p1w + l * C * F;
      const float* p1b_l  = p1b + l * F;
      const float* p2w_l  = p2w + l * F * F;
      const float* p2b_l  = p2b + l * F;
      const float* semw_l = semw + l * F * H;
      const float* semb_l = semb + l * H;
      const float* n1w_l  = n1w + l * 384 * F;
      const float* n1b_l  = n1b + l * F;
      const float* n2w_l  = n2w + l * F * F;
      const float* n2b_l  = n2b + l * F;
      const float* v1w_l  = v1w + l * F * F;
      const float* v1b_l  = v1b + l * F;
      const float* v2w_l  = v2w + l * F;
      const float* c1w_l  = c1w + l * 2 * F * F;
      const float* c1b_l  = c1b + l * F;
      const float* c2w_l  = c2w + l * F;

      k_pre<<<BN, 256, 0, stream>>>(h0, hw, einw_l, eo1w_l, hkA[0], hkB[0], e1A[0], e1B[0]);
      // step 0: in set0 -> out set1 ; step 1: in set1 -> out set0 ; step 2: in set0, tail
      k_edge<<<BN * 2, 256, 0, stream>>>(xb, hkA[0], hkB[0], e1A[0], e1B[0],
          einb_l, rbm_l, rbb_l, eo1w_l, eo1b_l, eo2w_l, eo2b_l, xmix_l, semw_l, semb_l,
          mS, Up, cp);
      k_comb<1, 0><<<BN, 256, 0, stream>>>(hw, mS, Up, cp,
          p1w_l, p1b_l, p2w_l, p2b_l, n1w_l, n1b_l, n2w_l, n2b_l,
          einw_l, eo1w_l, hkA[1], hkB[1], e1A[1], e1B[1],
          c1w_l, v1w_l, v1b_l, v2w_l, uA, uB, mbuf);
      k_edge<<<BN * 2, 256, 0, stream>>>(xb, hkA[1], hkB[1], e1A[1], e1B[1],
          einb_l, rbm_l, rbb_l, eo1w_l, eo1b_l, eo2w_l, eo2b_l, xmix_l, semw_l, semb_l,
          mS, Up, cp);
      k_comb<1, 0><<<BN, 256, 0, stream>>>(hw, mS, Up, cp,
          p1w_l, p1b_l, p2w_l, p2b_l, n1w_l, n1b_l, n2w_l, n2b_l,
          einw_l, eo1w_l, hkA[0], hkB[0], e1A[0], e1B[0],
          c1w_l, v1w_l, v1b_l, v2w_l, uA, uB, mbuf);
      k_edge<<<BN * 2, 256, 0, stream>>>(xb, hkA[0], hkB[0], e1A[0], e1B[0],
          einb_l, rbm_l, rbb_l, eo1w_l, eo1b_l, eo2w_l, eo2b_l, xmix_l, semw_l, semb_l,
          mS, Up, cp);
      k_comb<0, 1><<<BN, 256, 0, stream>>>(hw, mS, Up, cp,
          p1w_l, p1b_l, p2w_l, p2b_l, n1w_l, n1b_l, n2w_l, n2b_l,
          einw_l, eo1w_l, hkA[1], hkB[1], e1A[1], e1B[1],
          c1w_l, v1w_l, v1b_l, v2w_l, uA, uB, mbuf);
      k_tail<<<BN, 256, 0, stream>>>(xb, uA, uB, c1b_l, c2w_l, dvb);
      k_fin<<<B, 128, 0, stream>>>(xb, vb, dvb, mbuf, sld);
    }
  }
  k_out<<<6, 256, 0, stream>>>(xw, vw, sld, (float*)d_out);
}

// Round 9
// 1087.936 us; speedup vs baseline: 3.6412x; 1.0092x over previous
//
#include <hip/hip_runtime.h>
#include <math.h>

namespace {

constexpr int B = 4, N = 128, FIN = 16, F = 64, H = 4, K = 50, C = 256;
constexpr int BN = B * N;
constexpr float EPS = 1e-5f;

__device__ __forceinline__ float silu_f(float x) { return x / (1.0f + __expf(-x)); }
__device__ __forceinline__ float tanh_f(float x) { return 1.0f - 2.0f / (__expf(2.0f * x) + 1.0f); }

__global__ void k_init(const float* __restrict__ x, const float* __restrict__ v,
                       float* __restrict__ xw, float* __restrict__ vw, float* __restrict__ sld) {
  int t = blockIdx.x * blockDim.x + threadIdx.x;
  if (t < B * N * 3) { xw[t] = x[t]; vw[t] = v[t]; }
  if (t < B) sld[t] = 0.0f;
}

__global__ __launch_bounds__(F) void k_embed(const float* __restrict__ hin,
    const float* __restrict__ w1, const float* __restrict__ b1,
    const float* __restrict__ w2, const float* __restrict__ b2, float* __restrict__ h0) {
  int node = blockIdx.x, f = threadIdx.x;
  __shared__ float t1[F];
  float acc = b1[f];
  #pragma unroll
  for (int r = 0; r < FIN; ++r) acc += hin[node * FIN + r] * w1[r * F + f];
  t1[f] = silu_f(acc);
  __syncthreads();
  float a0 = b2[f], a1 = 0.f, a2 = 0.f, a3 = 0.f;
  #pragma unroll
  for (int r = 0; r < F; r += 4) {
    a0 += t1[r] * w2[r * F + f];
    a1 += t1[r + 1] * w2[(r + 1) * F + f];
    a2 += t1[r + 2] * w2[(r + 2) * F + f];
    a3 += t1[r + 3] * w2[(r + 3) * F + f];
  }
  h0[node * F + f] = (a0 + a1) + (a2 + a3);
}

// Per-node precomputation at flow start: hkA/hkB (edge_in halves), e1A/e1B (eo1 halves).
__global__ __launch_bounds__(256) void k_pre(const float* __restrict__ h0, float* __restrict__ hw,
    const float* __restrict__ ein_w, const float* __restrict__ eo1w,
    float* __restrict__ hkA, float* __restrict__ hkB,
    float* __restrict__ e1A, float* __restrict__ e1B) {
  int node = blockIdx.x, t = threadIdx.x;
  __shared__ float s_h[F];
  if (t < F) s_h[t] = h0[node * F + t];
  __syncthreads();
  if (t < F) hw[node * F + t] = s_h[t];
  if (t < 228) {
    float a0 = 0.f, a1 = 0.f, a2 = 0.f, a3 = 0.f;
    if (t < 50) { int k = t;
      #pragma unroll
      for (int r = 0; r < F; r += 4) {
        a0 += s_h[r] * ein_w[r * K + k];       a1 += s_h[r + 1] * ein_w[(r + 1) * K + k];
        a2 += s_h[r + 2] * ein_w[(r + 2) * K + k]; a3 += s_h[r + 3] * ein_w[(r + 3) * K + k];
      }
      hkA[node * K + k] = (a0 + a1) + (a2 + a3);
    } else if (t < 100) { int k = t - 50;
      #pragma unroll
      for (int r = 0; r < F; r += 4) {
        a0 += s_h[r] * ein_w[(F + r) * K + k];       a1 += s_h[r + 1] * ein_w[(F + r + 1) * K + k];
        a2 += s_h[r + 2] * ein_w[(F + r + 2) * K + k]; a3 += s_h[r + 3] * ein_w[(F + r + 3) * K + k];
      }
      hkB[node * K + k] = (a0 + a1) + (a2 + a3);
    } else if (t < 164) { int c = t - 100;
      #pragma unroll
      for (int r = 0; r < F; r += 4) {
        a0 += s_h[r] * eo1w[r * F + c];       a1 += s_h[r + 1] * eo1w[(r + 1) * F + c];
        a2 += s_h[r + 2] * eo1w[(r + 2) * F + c]; a3 += s_h[r + 3] * eo1w[(r + 3) * F + c];
      }
      e1A[node * F + c] = (a0 + a1) + (a2 + a3);
    } else { int c = t - 164;
      #pragma unroll
      for (int r = 0; r < F; r += 4) {
        a0 += s_h[r] * eo1w[(F + r) * F + c];       a1 += s_h[r + 1] * eo1w[(F + r + 1) * F + c];
        a2 += s_h[r + 2] * eo1w[(F + r + 2) * F + c]; a3 += s_h[r + 3] * eo1w[(F + r + 3) * F + c];
      }
      e1B[node * F + c] = (a0 + a1) + (a2 + a3);
    }
  }
}

// Heavy half-step kernel: one block per (b, i, j-half). 256 threads / 4 waves.
// Grid = BN*2 = 1024 blocks; 128-VGPR bracket + 38.5KB LDS -> 4 blocks/CU.
// Edge-A zk is double-buffered per wave: zk(j+1) is produced into the alternate
// buffer before the dot-product reads zk(j), hiding the LDS write->read latency;
// hkB/e1B globals are prefetched 2 iterations ahead.
__global__ __launch_bounds__(256, 2) void k_edge(
    const float* __restrict__ xp,
    const float* __restrict__ hkA_in, const float* __restrict__ hkB_in,
    const float* __restrict__ e1A_in, const float* __restrict__ e1B_in,
    const float* __restrict__ ein_b, const float* __restrict__ rbf_m, const float* __restrict__ rbf_b,
    const float* __restrict__ eo1w, const float* __restrict__ eo1b,
    const float* __restrict__ eo2w, const float* __restrict__ eo2b,
    const float* __restrict__ xmix,
    const float* __restrict__ semw, const float* __restrict__ semb,
    float* __restrict__ mS, float* __restrict__ Upart, float* __restrict__ combpart) {
  int blk = blockIdx.x;
  int b = blk >> 8, i = (blk >> 1) & 127, jh = blk & 1;
  int t = threadIdx.x, w = t >> 6, lane = t & 63;
  int bN = b * N;
  int bi2 = ((bN + i) << 1) + jh;

  __shared__ __align__(16) float s_heT[64 * 68];   // he transposed [r][j_local], pad 68
  __shared__ __align__(16) float s_union[4352];    // t1buf (edge) / {cpart, att}
  __shared__ __align__(16) float4 s_dxn[64];       // (dx0,dx1,dx2,dn) for local j
  __shared__ float s_inv[64];
  __shared__ float s_zkbase[K];
  __shared__ float s_e1base[F];
  __shared__ __align__(16) float s_zk[4][2][56];   // per-wave double-buffered zk

  float* t1buf   = s_union;          // [64][68] during edge
  float* s_cpart = s_union;          // [4][256][3] = 3072 after edge
  float* s_att   = s_union + 3072;   // [4][64] unnormalized e

  // ---- staging (no xpos staging: dxn computed straight from global, L2-hot) ----
  if (t < K) s_zkbase[t] = hkA_in[(bN + i) * K + t] + ein_b[t];
  if (t >= 64 && t < 128) s_e1base[t - 64] = e1A_in[(bN + i) * F + (t - 64)] + eo1b[t - 64];
  if (lane >= 50 && lane < 56) { s_zk[w][0][lane] = 0.f; s_zk[w][1][lane] = 0.f; }  // float4 pads
  if (t < 64) {
    const float* xb_ = xp + bN * 3;
    int jg = jh * 64 + t;
    float dx0 = xb_[i * 3 + 0] - xb_[jg * 3 + 0];
    float dx1 = xb_[i * 3 + 1] - xb_[jg * 3 + 1];
    float dx2 = xb_[i * 3 + 2] - xb_[jg * 3 + 2];
    float dn = sqrtf(dx0 * dx0 + dx1 * dx1 + dx2 * dx2 + EPS * EPS);
    s_dxn[t] = make_float4(dx0, dx1, dx2, dn);
    s_inv[t] = 1.0f / (dn + EPS);
  }
  __syncthreads();

  float rbm = 0.f, rbb = 0.f;
  if (lane < K) { rbm = rbf_m[lane]; rbb = rbf_b[lane]; }

  // ---- edge phase: wave w owns local j in [w*16, w*16+16) ----
  {
    int jbl = w * 16;               // local base
    int jbg = jh * 64 + jbl;        // global base
    {  // sub-pass A: t1 rows (only wk live); zk software-pipelined
      float wk[52];
      #pragma unroll
      for (int k = 0; k < 50; ++k) wk[k] = eo1w[(128 + k) * F + lane];
      wk[50] = 0.f; wk[51] = 0.f;
      float w1d = eo1w[178 * F + lane];
      float e1b_lane = s_e1base[lane];
      // prologue: j0 loads + zk(j0) into buf0; then j1 loads
      float hk0 = (lane < K) ? hkB_in[(bN + jbg) * K + lane] : 0.f;
      float e1_c = e1B_in[(bN + jbg) * F + lane];
      if (lane < K) {
        float dn0 = s_dxn[jbl].w;
        float e = __expf(-dn0) - rbm;
        s_zk[w][0][lane] = __expf(-rbb * e * e) * (s_zkbase[lane] + hk0);
      }
      float hk_n = (lane < K) ? hkB_in[(bN + jbg + 1) * K + lane] : 0.f;
      float e1_n = e1B_in[(bN + jbg + 1) * F + lane];
      for (int jj = 0; jj < 16; ++jj) {
        int jl = jbl + jj;
        int cur = jj & 1;
        if (jj < 15) {  // produce zk(jj+1) into the other buffer (hides LDS rt-latency)
          if (lane < K) {
            float dn1 = s_dxn[jl + 1].w;
            float e = __expf(-dn1) - rbm;
            s_zk[w][cur ^ 1][lane] = __expf(-rbb * e * e) * (s_zkbase[lane] + hk_n);
          }
        }
        float e1v = e1_c;
        if (jj < 14) {  // prefetch jj+2 globals
          hk_n = (lane < K) ? hkB_in[(bN + jbg + jj + 2) * K + lane] : 0.f;
          e1_c = e1_n;
          e1_n = e1B_in[(bN + jbg + jj + 2) * F + lane];
        } else {
          e1_c = e1_n;
        }
        float dn = s_dxn[jl].w;
        float ac0 = e1b_lane + e1v + dn * w1d, ac1 = 0.f, ac2 = 0.f, ac3 = 0.f;
        const float4* z4 = (const float4*)(&s_zk[w][cur][0]);
        #pragma unroll
        for (int k4 = 0; k4 < 13; ++k4) {
          float4 z = z4[k4];
          ac0 += z.x * wk[4 * k4];     ac1 += z.y * wk[4 * k4 + 1];
          ac2 += z.z * wk[4 * k4 + 2]; ac3 += z.w * wk[4 * k4 + 3];
        }
        t1buf[jl * 68 + lane] = silu_f((ac0 + ac1) + (ac2 + ac3));
      }
    }
    // same-wave rows -> no barrier needed
    {  // sub-pass B: he = t1 @ eo2 (only er live), b128-packed writes into he_T
      float er[64];
      #pragma unroll
      for (int r = 0; r < F; ++r) er[r] = eo2w[r * F + lane];
      float b2 = eo2b[lane];
      for (int jj4 = 0; jj4 < 4; ++jj4) {
        float hv[4];
        #pragma unroll
        for (int q = 0; q < 4; ++q) {
          const float4* t4 = (const float4*)(&t1buf[(jbl + jj4 * 4 + q) * 68]);
          float ac0 = b2, ac1 = 0.f, ac2 = 0.f, ac3 = 0.f;
          #pragma unroll
          for (int r4 = 0; r4 < 16; ++r4) {
            float4 tt = t4[r4];
            ac0 += tt.x * er[4 * r4];     ac1 += tt.y * er[4 * r4 + 1];
            ac2 += tt.z * er[4 * r4 + 2]; ac3 += tt.w * er[4 * r4 + 3];
          }
          hv[q] = (ac0 + ac1) + (ac2 + ac3);
        }
        *(float4*)(&s_heT[lane * 68 + jbl + jj4 * 4]) = make_float4(hv[0], hv[1], hv[2], hv[3]);
      }
    }
  }
  __syncthreads();  // he_T complete; t1buf dead -> union becomes cpart/att

  // ---- coeff partial: register-tiled 8j x 4c, 2 passes over this wave's 16 j ----
  {
    int c0 = 4 * (t & 63);
    float4 aX = make_float4(0.f, 0.f, 0.f, 0.f);
    float4 aY = make_float4(0.f, 0.f, 0.f, 0.f);
    float4 aZ = make_float4(0.f, 0.f, 0.f, 0.f);
    #pragma unroll 1
    for (int p = 0; p < 2; ++p) {
      int j0 = w * 16 + p * 8;   // local j
      float4 cacc[8];
      #pragma unroll
      for (int jj = 0; jj < 8; ++jj) cacc[jj] = make_float4(0.f, 0.f, 0.f, 0.f);
      for (int r = 0; r < 64; ++r) {
        float4 xm4 = *(const float4*)(&xmix[r * C + c0]);
        const float4* hb = (const float4*)(&s_heT[r * 68 + j0]);
        float4 h0v = hb[0], h1v = hb[1];
#define CSTEP(idx, hval) \
        cacc[idx].x += (hval) * xm4.x; cacc[idx].y += (hval) * xm4.y; \
        cacc[idx].z += (hval) * xm4.z; cacc[idx].w += (hval) * xm4.w;
        CSTEP(0, h0v.x)  CSTEP(1, h0v.y)  CSTEP(2, h0v.z)  CSTEP(3, h0v.w)
        CSTEP(4, h1v.x)  CSTEP(5, h1v.y)  CSTEP(6, h1v.z)  CSTEP(7, h1v.w)
#undef CSTEP
      }
      #pragma unroll
      for (int jj = 0; jj < 8; ++jj) {
        int jl = j0 + jj;
        float4 dq = s_dxn[jl];
        float inv = s_inv[jl];
        float s0 = tanh_f(cacc[jj].x) * inv;
        float s1 = tanh_f(cacc[jj].y) * inv;
        float s2 = tanh_f(cacc[jj].z) * inv;
        float s3 = tanh_f(cacc[jj].w) * inv;
        aX.x += dq.x * s0; aY.x += dq.y * s0; aZ.x += dq.z * s0;
        aX.y += dq.x * s1; aY.y += dq.y * s1; aZ.y += dq.z * s1;
        aX.z += dq.x * s2; aY.z += dq.y * s2; aZ.z += dq.z * s2;
        aX.w += dq.x * s3; aY.w += dq.y * s3; aZ.w += dq.z * s3;
      }
    }
    int cb = w * 768 + c0 * 3;
    s_cpart[cb + 0] = aX.x; s_cpart[cb + 1] = aY.x; s_cpart[cb + 2]  = aZ.x;
    s_cpart[cb + 3] = aX.y; s_cpart[cb + 4] = aY.y; s_cpart[cb + 5]  = aZ.y;
    s_cpart[cb + 6] = aX.z; s_cpart[cb + 7] = aY.z; s_cpart[cb + 8]  = aZ.z;
    s_cpart[cb + 9] = aX.w; s_cpart[cb + 10] = aY.w; s_cpart[cb + 11] = aZ.w;
  }
  __syncthreads();

  // ---- combine the 4 wave partials of comb -> global ----
  {
    int c = t;
    float q0 = s_cpart[c * 3 + 0] + s_cpart[768 + c * 3 + 0] + s_cpart[1536 + c * 3 + 0] + s_cpart[2304 + c * 3 + 0];
    float q1 = s_cpart[c * 3 + 1] + s_cpart[768 + c * 3 + 1] + s_cpart[1536 + c * 3 + 1] + s_cpart[2304 + c * 3 + 1];
    float q2 = s_cpart[c * 3 + 2] + s_cpart[768 + c * 3 + 2] + s_cpart[1536 + c * 3 + 2] + s_cpart[2304 + c * 3 + 2];
    combpart[bi2 * 768 + c * 3 + 0] = q0;
    combpart[bi2 * 768 + c * 3 + 1] = q1;
    combpart[bi2 * 768 + c * 3 + 2] = q2;
  }

  // ---- logits: thread t -> (j_local = t&63, head = t>>6 = w); column reads ----
  {
    int jl = t & 63, hh = w;
    int jg = jh * 64 + jl;
    float l0a = 0.f, l0b = 0.f;
    #pragma unroll 8
    for (int r = 0; r < 64; r += 2) {
      float hv0 = s_heT[r * 68 + jl];
      float hv1 = s_heT[(r + 1) * 68 + jl];
      l0a += hv0 * semw[r * H + hh];
      l0b += hv1 * semw[(r + 1) * H + hh];
    }
    float lg = semb[hh] + l0a + l0b;
    lg = lg > 0.f ? lg : 2.0f * (__expf(0.5f * lg) - 1.0f);  // celu alpha=2
    if (jg == i) lg -= 1e5f;
    float m = lg;
    #pragma unroll
    for (int off = 32; off > 0; off >>= 1) m = fmaxf(m, __shfl_xor(m, off));
    float e = __expf(lg - m);
    float S = e;
    #pragma unroll
    for (int off = 32; off > 0; off >>= 1) S += __shfl_xor(S, off);
    s_att[hh * 64 + jl] = e;
    if (lane == 0) { mS[bi2 * 8 + hh * 2] = m; mS[bi2 * 8 + hh * 2 + 1] = S; }
  }
  __syncthreads();

  // ---- U partial: thread t -> (f = t>>2, head = t&3); j-contiguous b128 reads ----
  {
    int f = t >> 2, hh = t & 3;
    const float4* hr = (const float4*)(&s_heT[f * 68]);
    const float4* ar = (const float4*)(&s_att[hh * 64]);
    float ac0 = 0.f, ac1 = 0.f, ac2 = 0.f, ac3 = 0.f;
    #pragma unroll 8
    for (int jg4 = 0; jg4 < 16; ++jg4) {
      float4 hv = hr[jg4];
      float4 av = ar[jg4];
      ac0 += hv.x * av.x; ac1 += hv.y * av.y; ac2 += hv.z * av.z; ac3 += hv.w * av.w;
    }
    Upart[bi2 * 256 + t] = (ac0 + ac1) + (ac2 + ac3);
  }
}

// Light combine kernel: one block per (b,i). Rescale-combine softmax halves,
// hcin, node MLPs + residual, plus PRE (next-step precomp) or TAIL outputs.
template<int PRE, int TAIL>
__global__ __launch_bounds__(256, 2) void k_comb(
    float* __restrict__ hw,
    const float* __restrict__ mS, const float* __restrict__ Upart, const float* __restrict__ combpart,
    const float* __restrict__ p1w, const float* __restrict__ p1b,
    const float* __restrict__ p2w, const float* __restrict__ p2b,
    const float* __restrict__ n1w, const float* __restrict__ n1b,
    const float* __restrict__ n2w, const float* __restrict__ n2b,
    const float* __restrict__ ein_w, const float* __restrict__ eo1w,
    float* __restrict__ hkA_out, float* __restrict__ hkB_out,
    float* __restrict__ e1A_out, float* __restrict__ e1B_out,
    const float* __restrict__ c1w, const float* __restrict__ v1w, const float* __restrict__ v1b,
    const float* __restrict__ v2w,
    float* __restrict__ uA, float* __restrict__ uB, float* __restrict__ mbuf) {
  int blk = blockIdx.x, b = blk >> 7, i = blk & 127;
  int t = threadIdx.x, w = t >> 6, lane = t & 63;
  int bN = b * N;
  int bi2 = (bN + i) << 1;
  constexpr float invN = 1.0f / (float)N;

  __shared__ float s_hcin[C];
  __shared__ float s_cat[384];
  __shared__ float s_part[4][F];
  __shared__ float s_vec[F];
  __shared__ float s_hnew[F];

  float hi_val = (t < F) ? hw[(bN + i) * F + t] : 0.f;

  // ---- h_e combine (flash-style rescale) ----
  {
    int hh = t & 3;
    float m0 = mS[bi2 * 8 + hh * 2],       S0 = mS[bi2 * 8 + hh * 2 + 1];
    float m1 = mS[(bi2 + 1) * 8 + hh * 2], S1 = mS[(bi2 + 1) * 8 + hh * 2 + 1];
    float m = fmaxf(m0, m1);
    float w0 = __expf(m0 - m), w1 = __expf(m1 - m);
    float u = w0 * Upart[bi2 * 256 + t] + w1 * Upart[(bi2 + 1) * 256 + t];
    s_cat[64 + t] = u / (w0 * S0 + w1 * S1);
  }
  // ---- hcin combine ----
  {
    int c = t;
    float q0 = (combpart[bi2 * 768 + c * 3 + 0] + combpart[(bi2 + 1) * 768 + c * 3 + 0]) * invN;
    float q1 = (combpart[bi2 * 768 + c * 3 + 1] + combpart[(bi2 + 1) * 768 + c * 3 + 1]) * invN;
    float q2 = (combpart[bi2 * 768 + c * 3 + 2] + combpart[(bi2 + 1) * 768 + c * 3 + 2]) * invN;
    s_hcin[c] = q0 * q0 + q1 * q1 + q2 * q2;
  }
  __syncthreads();

  // ---- node phase (proven 256-thread version) ----
  {
    int c0 = w * 64;
    float a0 = 0.f, a1 = 0.f, a2 = 0.f, a3 = 0.f;
    #pragma unroll 8
    for (int cc = 0; cc < 64; cc += 4) {
      a0 += s_hcin[c0 + cc] * p1w[(c0 + cc) * F + lane];
      a1 += s_hcin[c0 + cc + 1] * p1w[(c0 + cc + 1) * F + lane];
      a2 += s_hcin[c0 + cc + 2] * p1w[(c0 + cc + 2) * F + lane];
      a3 += s_hcin[c0 + cc + 3] * p1w[(c0 + cc + 3) * F + lane];
    }
    s_part[w][lane] = (a0 + a1) + (a2 + a3);
  }
  __syncthreads();
  if (t < F) s_vec[t] = silu_f(s_part[0][t] + s_part[1][t] + s_part[2][t] + s_part[3][t] + p1b[t]);
  __syncthreads();
  if (t < F) {
    float a0 = p2b[t], a1 = 0.f, a2 = 0.f, a3 = 0.f;
    #pragma unroll 8
    for (int r = 0; r < F; r += 4) {
      a0 += s_vec[r] * p2w[r * F + t];
      a1 += s_vec[r + 1] * p2w[(r + 1) * F + t];
      a2 += s_vec[r + 2] * p2w[(r + 2) * F + t];
      a3 += s_vec[r + 3] * p2w[(r + 3) * F + t];
    }
    s_cat[t] = hi_val;
    s_cat[320 + t] = silu_f((a0 + a1) + (a2 + a3));
  }
  __syncthreads();
  {
    int r0 = w * 96;
    float a0 = 0.f, a1 = 0.f, a2 = 0.f, a3 = 0.f;
    #pragma unroll 8
    for (int rr = 0; rr < 96; rr += 4) {
      a0 += s_cat[r0 + rr] * n1w[(r0 + rr) * F + lane];
      a1 += s_cat[r0 + rr + 1] * n1w[(r0 + rr + 1) * F + lane];
      a2 += s_cat[r0 + rr + 2] * n1w[(r0 + rr + 2) * F + lane];
      a3 += s_cat[r0 + rr + 3] * n1w[(r0 + rr + 3) * F + lane];
    }
    s_part[w][lane] = (a0 + a1) + (a2 + a3);
  }
  __syncthreads();
  if (t < F) s_vec[t] = silu_f(s_part[0][t] + s_part[1][t] + s_part[2][t] + s_part[3][t] + n1b[t]);
  __syncthreads();
  if (t < F) {
    float a0 = n2b[t], a1 = 0.f, a2 = 0.f, a3 = 0.f;
    #pragma unroll 8
    for (int r = 0; r < F; r += 4) {
      a0 += s_vec[r] * n2w[r * F + t];
      a1 += s_vec[r + 1] * n2w[(r + 1) * F + t];
      a2 += s_vec[r + 2] * n2w[(r + 2) * F + t];
      a3 += s_vec[r + 3] * n2w[(r + 3) * F + t];
    }
    float hn = hi_val + silu_f((a0 + a1) + (a2 + a3));
    s_hnew[t] = hn;
    hw[(bN + i) * F + t] = hn;
  }
  __syncthreads();

  if (PRE) {  // next-step node precomp from updated h
    if (t < 228) {
      float a0 = 0.f, a1 = 0.f, a2 = 0.f, a3 = 0.f;
      if (t < 50) { int k = t;
        #pragma unroll
        for (int r = 0; r < F; r += 4) {
          a0 += s_hnew[r] * ein_w[r * K + k];       a1 += s_hnew[r + 1] * ein_w[(r + 1) * K + k];
          a2 += s_hnew[r + 2] * ein_w[(r + 2) * K + k]; a3 += s_hnew[r + 3] * ein_w[(r + 3) * K + k];
        }
        hkA_out[(bN + i) * K + k] = (a0 + a1) + (a2 + a3);
      } else if (t < 100) { int k = t - 50;
        #pragma unroll
        for (int r = 0; r < F; r += 4) {
          a0 += s_hnew[r] * ein_w[(F + r) * K + k];       a1 += s_hnew[r + 1] * ein_w[(F + r + 1) * K + k];
          a2 += s_hnew[r + 2] * ein_w[(F + r + 2) * K + k]; a3 += s_hnew[r + 3] * ein_w[(F + r + 3) * K + k];
        }
        hkB_out[(bN + i) * K + k] = (a0 + a1) + (a2 + a3);
      } else if (t < 164) { int c = t - 100;
        #pragma unroll
        for (int r = 0; r < F; r += 4) {
          a0 += s_hnew[r] * eo1w[r * F + c];       a1 += s_hnew[r + 1] * eo1w[(r + 1) * F + c];
          a2 += s_hnew[r + 2] * eo1w[(r + 2) * F + c]; a3 += s_hnew[r + 3] * eo1w[(r + 3) * F + c];
        }
        e1A_out[(bN + i) * F + c] = (a0 + a1) + (a2 + a3);
      } else { int c = t - 164;
        #pragma unroll
        for (int r = 0; r < F; r += 4) {
          a0 += s_hnew[r] * eo1w[(F + r) * F + c];       a1 += s_hnew[r + 1] * eo1w[(F + r + 1) * F + c];
          a2 += s_hnew[r + 2] * eo1w[(F + r + 2) * F + c]; a3 += s_hnew[r + 3] * eo1w[(F + r + 3) * F + c];
        }
        e1B_out[(bN + i) * F + c] = (a0 + a1) + (a2 + a3);
      }
    }
  }
  if (TAIL) {  // coord1 halves + vel scalar m for the flow tail
    if (w == 0) {
      float a0 = 0.f, a1 = 0.f, a2 = 0.f, a3 = 0.f;
      #pragma unroll
      for (int r = 0; r < F; r += 4) {
        a0 += s_hnew[r] * c1w[r * F + lane];       a1 += s_hnew[r + 1] * c1w[(r + 1) * F + lane];
        a2 += s_hnew[r + 2] * c1w[(r + 2) * F + lane]; a3 += s_hnew[r + 3] * c1w[(r + 3) * F + lane];
      }
      uA[(bN + i) * F + lane] = (a0 + a1) + (a2 + a3);
    } else if (w == 1) {
      float a0 = 0.f, a1 = 0.f, a2 = 0.f, a3 = 0.f;
      #pragma unroll
      for (int r = 0; r < F; r += 4) {
        a0 += s_hnew[r] * c1w[(F + r) * F + lane];       a1 += s_hnew[r + 1] * c1w[(F + r + 1) * F + lane];
        a2 += s_hnew[r + 2] * c1w[(F + r + 2) * F + lane]; a3 += s_hnew[r + 3] * c1w[(F + r + 3) * F + lane];
      }
      uB[(bN + i) * F + lane] = (a0 + a1) + (a2 + a3);
    } else if (w == 2) {
      float a0 = v1b[lane], a1 = 0.f, a2 = 0.f, a3 = 0.f;
      #pragma unroll
      for (int r = 0; r < F; r += 4) {
        a0 += s_hnew[r] * v1w[r * F + lane];       a1 += s_hnew[r + 1] * v1w[(r + 1) * F + lane];
        a2 += s_hnew[r + 2] * v1w[(r + 2) * F + lane]; a3 += s_hnew[r + 3] * v1w[(r + 3) * F + lane];
      }
      float tv = silu_f((a0 + a1) + (a2 + a3)) * v2w[lane];
      #pragma unroll
      for (int off = 32; off > 0; off >>= 1) tv += __shfl_down(tv, off);
      if (lane == 0) mbuf[bN + i] = tv;
    }
  }
}

// delta_v[b,i] = (1/N) sum_j (coord2 . silu(uA_i + uB_j + b)) * (x_i - x_j)
__global__ __launch_bounds__(256) void k_tail(const float* __restrict__ xb,
    const float* __restrict__ uA, const float* __restrict__ uB,
    const float* __restrict__ c1b, const float* __restrict__ c2w,
    float* __restrict__ dv) {
  int blk = blockIdx.x, b = blk >> 7, i = blk & 127;
  int t = threadIdx.x, w = t >> 6, lane = t & 63;
  __shared__ float s_xpos[N * 3];
  __shared__ float s_uAi[F];
  __shared__ float s_acc[4][3];
  for (int idx = t; idx < N * 3; idx += 256) s_xpos[idx] = xb[b * N * 3 + idx];
  if (t < F) s_uAi[t] = uA[(b * N + i) * F + t];
  __syncthreads();
  float xi0 = s_xpos[i * 3 + 0], xi1 = s_xpos[i * 3 + 1], xi2 = s_xpos[i * 3 + 2];
  float base = s_uAi[lane] + c1b[lane];
  float c2v = c2w[lane];
  float a0 = 0.f, a1 = 0.f, a2 = 0.f;
  for (int jj = 0; jj < 32; ++jj) {
    int j = w + 4 * jj;
    float tv = silu_f(base + uB[(b * N + j) * F + lane]) * c2v;
    #pragma unroll
    for (int off = 32; off > 0; off >>= 1) tv += __shfl_down(tv, off);
    if (lane == 0) {
      float dx0 = xi0 - s_xpos[j * 3 + 0];
      float dx1 = xi1 - s_xpos[j * 3 + 1];
      float dx2 = xi2 - s_xpos[j * 3 + 2];
      a0 += tv * dx0; a1 += tv * dx1; a2 += tv * dx2;
    }
  }
  if (lane == 0) { s_acc[w][0] = a0; s_acc[w][1] = a1; s_acc[w][2] = a2; }
  __syncthreads();
  if (t < 3) {
    float s = s_acc[0][t] + s_acc[1][t] + s_acc[2][t] + s_acc[3][t];
    dv[(b * N + i) * 3 + t] = s * (1.0f / (float)N);
  }
}

// apply v' = exp(m)*v + dv, x' = x + v'; center x and v; sld += 3*sum(m). One block per batch.
__global__ __launch_bounds__(128) void k_fin(float* __restrict__ xb, float* __restrict__ vb,
    const float* __restrict__ dv, const float* __restrict__ mbuf, float* __restrict__ sld) {
  int b = blockIdx.x, t = threadIdx.x;
  __shared__ float red[N];
  float m = mbuf[b * N + t];
  float em = __expf(m);
  float vv[3], xx[3];
  #pragma unroll
  for (int d = 0; d < 3; ++d) {
    int idx = (b * N + t) * 3 + d;
    vv[d] = em * vb[idx] + dv[idx];
    xx[d] = xb[idx] + vv[d];
  }
  #pragma unroll
  for (int d = 0; d < 3; ++d) {
    red[t] = xx[d];
    __syncthreads();
    for (int s = 64; s > 0; s >>= 1) { if (t < s) red[t] += red[t + s]; __syncthreads(); }
    xx[d] -= red[0] * (1.0f / (float)N);
    __syncthreads();
    red[t] = vv[d];
    __syncthreads();
    for (int s = 64; s > 0; s >>= 1) { if (t < s) red[t] += red[t + s]; __syncthreads(); }
    vv[d] -= red[0] * (1.0f / (float)N);
    __syncthreads();
  }
  #pragma unroll
  for (int d = 0; d < 3; ++d) {
    int idx = (b * N + t) * 3 + d;
    xb[idx] = xx[d];
    vb[idx] = vv[d];
  }
  red[t] = m;
  __syncthreads();
  for (int s = 64; s > 0; s >>= 1) { if (t < s) red[t] += red[t + s]; __syncthreads(); }
  if (t == 0) sld[b] += 3.0f * red[0];
}

__global__ void k_out(const float* __restrict__ xw, const float* __restrict__ vw,
                      const float* __restrict__ sld, float* __restrict__ out) {
  int t = blockIdx.x * blockDim.x + threadIdx.x;
  if (t < B * N * 3) { out[t] = xw[t]; out[B * N * 3 + t] = vw[t]; }
  if (t < B) out[2 * B * N * 3 + t] = sld[t];
}

}  // namespace

extern "C" void kernel_launch(void* const* d_in, const int* in_sizes, int n_in,
                              void* d_out, int out_size, void* d_ws, size_t ws_size,
                              hipStream_t stream) {
  const float* in_h   = (const float*)d_in[0];
  const float* in_x   = (const float*)d_in[1];
  const float* in_v   = (const float*)d_in[2];
  const float* emb1_w = (const float*)d_in[3];
  const float* emb1_b = (const float*)d_in[4];
  const float* emb2_w = (const float*)d_in[5];
  const float* emb2_b = (const float*)d_in[6];
  const float* ein_w  = (const float*)d_in[7];
  const float* ein_b  = (const float*)d_in[8];
  const float* rbf_m  = (const float*)d_in[9];
  const float* rbf_b  = (const float*)d_in[10];
  const float* eo1w   = (const float*)d_in[11];
  const float* eo1b   = (const float*)d_in[12];
  const float* eo2w   = (const float*)d_in[13];
  const float* eo2b   = (const float*)d_in[14];
  const float* xmix   = (const float*)d_in[15];
  const float* p1w    = (const float*)d_in[16];
  const float* p1b    = (const float*)d_in[17];
  const float* p2w    = (const float*)d_in[18];
  const float* p2b    = (const float*)d_in[19];
  const float* semw   = (const float*)d_in[20];
  const float* semb   = (const float*)d_in[21];
  const float* n1w    = (const float*)d_in[22];
  const float* n1b    = (const float*)d_in[23];
  const float* n2w    = (const float*)d_in[24];
  const float* n2b    = (const float*)d_in[25];
  const float* v1w    = (const float*)d_in[26];
  const float* v1b    = (const float*)d_in[27];
  const float* v2w    = (const float*)d_in[28];
  const float* c1w    = (const float*)d_in[29];
  const float* c1b    = (const float*)d_in[30];
  const float* c2w    = (const float*)d_in[31];

  float* ws   = (float*)d_ws;
  float* h0   = ws;                 // BN*F
  float* hw   = h0 + BN * F;        // BN*F
  float* hkA0 = hw + BN * F;        // BN*K
  float* hkB0 = hkA0 + BN * K;
  float* e1A0 = hkB0 + BN * K;      // BN*F
  float* e1B0 = e1A0 + BN * F;
  float* hkA1 = e1B0 + BN * F;
  float* hkB1 = hkA1 + BN * K;
  float* e1A1 = hkB1 + BN * K;
  float* e1B1 = e1A1 + BN * F;
  float* uA   = e1B1 + BN * F;      // BN*F
  float* uB   = uA + BN * F;
  float* xw   = uB + BN * F;        // BN*3
  float* vw   = xw + BN * 3;
  float* dvb  = vw + BN * 3;
  float* mbuf = dvb + BN * 3;       // BN
  float* sld  = mbuf + BN;          // B
  float* mS   = sld + B;            // BN*2*8
  float* Up   = mS + BN * 2 * 8;    // BN*2*256
  float* cp   = Up + BN * 2 * 256;  // BN*2*768

  k_init<<<6, 256, 0, stream>>>(in_x, in_v, xw, vw, sld);
  k_embed<<<BN, F, 0, stream>>>(in_h, emb1_w, emb1_b, emb2_w, emb2_b, h0);

  float* hkA[2] = {hkA0, hkA1};
  float* hkB[2] = {hkB0, hkB1};
  float* e1A[2] = {e1A0, e1A1};
  float* e1B[2] = {e1B0, e1B1};

  for (int dep = 0; dep < 2; ++dep) {
    for (int half = 0; half < 2; ++half) {
      int l = 2 * dep + half;
      float* xb = half ? vw : xw;
      float* vb = half ? xw : vw;
      const float* einw_l = ein_w + l * 2 * F * K;
      const float* einb_l = ein_b + l * K;
      const float* rbm_l  = rbf_m + l * K;
      const float* rbb_l  = rbf_b + l * K;
      const float* eo1w_l = eo1w + l * 179 * F;
      const float* eo1b_l = eo1b + l * F;
      const float* eo2w_l = eo2w + l * F * F;
      const float* eo2b_l = eo2b + l * F;
      const float* xmix_l = xmix + l * F * C;
      const float* p1w_l  = p1w + l * C * F;
      const float* p1b_l  = p1b + l * F;
      const float* p2w_l  = p2w + l * F * F;
      const float* p2b_l  = p2b + l * F;
      const float* semw_l = semw + l * F * H;
      const float* semb_l = semb + l * H;
      const float* n1w_l  = n1w + l * 384 * F;
      const float* n1b_l  = n1b + l * F;
      const float* n2w_l  = n2w + l * F * F;
      const float* n2b_l  = n2b + l * F;
      const float* v1w_l  = v1w + l * F * F;
      const float* v1b_l  = v1b + l * F;
      const float* v2w_l  = v2w + l * F;
      const float* c1w_l  = c1w + l * 2 * F * F;
      const float* c1b_l  = c1b + l * F;
      const float* c2w_l  = c2w + l * F;

      k_pre<<<BN, 256, 0, stream>>>(h0, hw, einw_l, eo1w_l, hkA[0], hkB[0], e1A[0], e1B[0]);
      // step 0: in set0 -> out set1 ; step 1: in set1 -> out set0 ; step 2: in set0, tail
      k_edge<<<BN * 2, 256, 0, stream>>>(xb, hkA[0], hkB[0], e1A[0], e1B[0],
          einb_l, rbm_l, rbb_l, eo1w_l, eo1b_l, eo2w_l, eo2b_l, xmix_l, semw_l, semb_l,
          mS, Up, cp);
      k_comb<1, 0><<<BN, 256, 0, stream>>>(hw, mS, Up, cp,
          p1w_l, p1b_l, p2w_l, p2b_l, n1w_l, n1b_l, n2w_l, n2b_l,
          einw_l, eo1w_l, hkA[1], hkB[1], e1A[1], e1B[1],
          c1w_l, v1w_l, v1b_l, v2w_l, uA, uB, mbuf);
      k_edge<<<BN * 2, 256, 0, stream>>>(xb, hkA[1], hkB[1], e1A[1], e1B[1],
          einb_l, rbm_l, rbb_l, eo1w_l, eo1b_l, eo2w_l, eo2b_l, xmix_l, semw_l, semb_l,
          mS, Up, cp);
      k_comb<1, 0><<<BN, 256, 0, stream>>>(hw, mS, Up, cp,
          p1w_l, p1b_l, p2w_l, p2b_l, n1w_l, n1b_l, n2w_l, n2b_l,
          einw_l, eo1w_l, hkA[0], hkB[0], e1A[0], e1B[0],
          c1w_l, v1w_l, v1b_l, v2w_l, uA, uB, mbuf);
      k_edge<<<BN * 2, 256, 0, stream>>>(xb, hkA[0], hkB[0], e1A[0], e1B[0],
          einb_l, rbm_l, rbb_l, eo1w_l, eo1b_l, eo2w_l, eo2b_l, xmix_l, semw_l, semb_l,
          mS, Up, cp);
      k_comb<0, 1><<<BN, 256, 0, stream>>>(hw, mS, Up, cp,
          p1w_l, p1b_l, p2w_l, p2b_l, n1w_l, n1b_l, n2w_l, n2b_l,
          einw_l, eo1w_l, hkA[1], hkB[1], e1A[1], e1B[1],
          c1w_l, v1w_l, v1b_l, v2w_l, uA, uB, mbuf);
      k_tail<<<BN, 256, 0, stream>>>(xb, uA, uB, c1b_l, c2w_l, dvb);
      k_fin<<<B, 128, 0, stream>>>(xb, vb, dvb, mbuf, sld);
    }
  }
  k_out<<<6, 256, 0, stream>>>(xw, vw, sld, (float*)d_out);
}

// Round 10
// 914.464 us; speedup vs baseline: 4.3319x; 1.1897x over previous
//
#include <hip/hip_runtime.h>
#include <math.h>

namespace {

constexpr int B = 4, N = 128, FIN = 16, F = 64, H = 4, K = 50, C = 256;
constexpr int BN = B * N;
constexpr float EPS = 1e-5f;

typedef float v2f __attribute__((ext_vector_type(2)));
__device__ __forceinline__ v2f mk2(float a, float b) { v2f r; r.x = a; r.y = b; return r; }

__device__ __forceinline__ float silu_f(float x) { return x / (1.0f + __expf(-x)); }
__device__ __forceinline__ float tanh_f(float x) { return 1.0f - 2.0f / (__expf(2.0f * x) + 1.0f); }

__global__ void k_init(const float* __restrict__ x, const float* __restrict__ v,
                       float* __restrict__ xw, float* __restrict__ vw, float* __restrict__ sld) {
  int t = blockIdx.x * blockDim.x + threadIdx.x;
  if (t < B * N * 3) { xw[t] = x[t]; vw[t] = v[t]; }
  if (t < B) sld[t] = 0.0f;
}

__global__ __launch_bounds__(F) void k_embed(const float* __restrict__ hin,
    const float* __restrict__ w1, const float* __restrict__ b1,
    const float* __restrict__ w2, const float* __restrict__ b2, float* __restrict__ h0) {
  int node = blockIdx.x, f = threadIdx.x;
  __shared__ float t1[F];
  float acc = b1[f];
  #pragma unroll
  for (int r = 0; r < FIN; ++r) acc += hin[node * FIN + r] * w1[r * F + f];
  t1[f] = silu_f(acc);
  __syncthreads();
  float a0 = b2[f], a1 = 0.f, a2 = 0.f, a3 = 0.f;
  #pragma unroll
  for (int r = 0; r < F; r += 4) {
    a0 += t1[r] * w2[r * F + f];
    a1 += t1[r + 1] * w2[(r + 1) * F + f];
    a2 += t1[r + 2] * w2[(r + 2) * F + f];
    a3 += t1[r + 3] * w2[(r + 3) * F + f];
  }
  h0[node * F + f] = (a0 + a1) + (a2 + a3);
}

// Per-node precomputation at flow start: hkA/hkB (edge_in halves), e1A/e1B (eo1 halves).
__global__ __launch_bounds__(256) void k_pre(const float* __restrict__ h0, float* __restrict__ hw,
    const float* __restrict__ ein_w, const float* __restrict__ eo1w,
    float* __restrict__ hkA, float* __restrict__ hkB,
    float* __restrict__ e1A, float* __restrict__ e1B) {
  int node = blockIdx.x, t = threadIdx.x;
  __shared__ float s_h[F];
  if (t < F) s_h[t] = h0[node * F + t];
  __syncthreads();
  if (t < F) hw[node * F + t] = s_h[t];
  if (t < 228) {
    float a0 = 0.f, a1 = 0.f, a2 = 0.f, a3 = 0.f;
    if (t < 50) { int k = t;
      #pragma unroll
      for (int r = 0; r < F; r += 4) {
        a0 += s_h[r] * ein_w[r * K + k];       a1 += s_h[r + 1] * ein_w[(r + 1) * K + k];
        a2 += s_h[r + 2] * ein_w[(r + 2) * K + k]; a3 += s_h[r + 3] * ein_w[(r + 3) * K + k];
      }
      hkA[node * K + k] = (a0 + a1) + (a2 + a3);
    } else if (t < 100) { int k = t - 50;
      #pragma unroll
      for (int r = 0; r < F; r += 4) {
        a0 += s_h[r] * ein_w[(F + r) * K + k];       a1 += s_h[r + 1] * ein_w[(F + r + 1) * K + k];
        a2 += s_h[r + 2] * ein_w[(F + r + 2) * K + k]; a3 += s_h[r + 3] * ein_w[(F + r + 3) * K + k];
      }
      hkB[node * K + k] = (a0 + a1) + (a2 + a3);
    } else if (t < 164) { int c = t - 100;
      #pragma unroll
      for (int r = 0; r < F; r += 4) {
        a0 += s_h[r] * eo1w[r * F + c];       a1 += s_h[r + 1] * eo1w[(r + 1) * F + c];
        a2 += s_h[r + 2] * eo1w[(r + 2) * F + c]; a3 += s_h[r + 3] * eo1w[(r + 3) * F + c];
      }
      e1A[node * F + c] = (a0 + a1) + (a2 + a3);
    } else { int c = t - 164;
      #pragma unroll
      for (int r = 0; r < F; r += 4) {
        a0 += s_h[r] * eo1w[(F + r) * F + c];       a1 += s_h[r + 1] * eo1w[(F + r + 1) * F + c];
        a2 += s_h[r + 2] * eo1w[(F + r + 2) * F + c]; a3 += s_h[r + 3] * eo1w[(F + r + 3) * F + c];
      }
      e1B[node * F + c] = (a0 + a1) + (a2 + a3);
    }
  }
}

// Heavy half-step kernel: one block per (b, i, j-half). 256 threads / 4 waves.
// Grid = BN*2 = 1024 blocks; 128-VGPR bracket + 38.5KB LDS -> 4 blocks/CU.
// All dot products use ext_vector float2 so the backend can emit v_pk_fma_f32
// (MI355X fp32 peak 157 TF = 2x fp64 comes from packed fp32; scalar FMA is half-rate).
__global__ __launch_bounds__(256, 2) void k_edge(
    const float* __restrict__ xp,
    const float* __restrict__ hkA_in, const float* __restrict__ hkB_in,
    const float* __restrict__ e1A_in, const float* __restrict__ e1B_in,
    const float* __restrict__ ein_b, const float* __restrict__ rbf_m, const float* __restrict__ rbf_b,
    const float* __restrict__ eo1w, const float* __restrict__ eo1b,
    const float* __restrict__ eo2w, const float* __restrict__ eo2b,
    const float* __restrict__ xmix,
    const float* __restrict__ semw, const float* __restrict__ semb,
    float* __restrict__ mS, float* __restrict__ Upart, float* __restrict__ combpart) {
  int blk = blockIdx.x;
  int b = blk >> 8, i = (blk >> 1) & 127, jh = blk & 1;
  int t = threadIdx.x, w = t >> 6, lane = t & 63;
  int bN = b * N;
  int bi2 = ((bN + i) << 1) + jh;

  __shared__ __align__(16) float s_heT[64 * 68];   // he transposed [r][j_local], pad 68
  __shared__ __align__(16) float s_union[4352];    // t1buf (edge) / {cpart, att}
  __shared__ __align__(16) float4 s_dxn[64];       // (dx0,dx1,dx2,dn) for local j
  __shared__ float s_inv[64];
  __shared__ float s_zkbase[K];
  __shared__ float s_e1base[F];
  __shared__ __align__(16) float s_zk[4][2][56];   // per-wave double-buffered zk

  float* t1buf   = s_union;          // [64][68] during edge
  float* s_cpart = s_union;          // [4][256][3] = 3072 after edge
  float* s_att   = s_union + 3072;   // [4][64] unnormalized e

  // ---- staging (no xpos staging: dxn computed straight from global, L2-hot) ----
  if (t < K) s_zkbase[t] = hkA_in[(bN + i) * K + t] + ein_b[t];
  if (t >= 64 && t < 128) s_e1base[t - 64] = e1A_in[(bN + i) * F + (t - 64)] + eo1b[t - 64];
  if (lane >= 50 && lane < 56) { s_zk[w][0][lane] = 0.f; s_zk[w][1][lane] = 0.f; }  // float4 pads
  if (t < 64) {
    const float* xb_ = xp + bN * 3;
    int jg = jh * 64 + t;
    float dx0 = xb_[i * 3 + 0] - xb_[jg * 3 + 0];
    float dx1 = xb_[i * 3 + 1] - xb_[jg * 3 + 1];
    float dx2 = xb_[i * 3 + 2] - xb_[jg * 3 + 2];
    float dn = sqrtf(dx0 * dx0 + dx1 * dx1 + dx2 * dx2 + EPS * EPS);
    s_dxn[t] = make_float4(dx0, dx1, dx2, dn);
    s_inv[t] = 1.0f / (dn + EPS);
  }
  __syncthreads();

  float rbm = 0.f, rbb = 0.f;
  if (lane < K) { rbm = rbf_m[lane]; rbb = rbf_b[lane]; }

  // ---- edge phase: wave w owns local j in [w*16, w*16+16) ----
  {
    int jbl = w * 16;               // local base
    int jbg = jh * 64 + jbl;        // global base
    {  // sub-pass A: t1 rows (only wk2 live); zk software-pipelined; packed FMAs
      v2f wk2[26];
      #pragma unroll
      for (int k = 0; k < 25; ++k)
        wk2[k] = mk2(eo1w[(128 + 2 * k) * F + lane], eo1w[(128 + 2 * k + 1) * F + lane]);
      wk2[25] = mk2(0.f, 0.f);
      float w1d = eo1w[178 * F + lane];
      float e1b_lane = s_e1base[lane];
      // prologue: j0 loads + zk(j0) into buf0; then j1 loads
      float hk0 = (lane < K) ? hkB_in[(bN + jbg) * K + lane] : 0.f;
      float e1_c = e1B_in[(bN + jbg) * F + lane];
      if (lane < K) {
        float dn0 = s_dxn[jbl].w;
        float e = __expf(-dn0) - rbm;
        s_zk[w][0][lane] = __expf(-rbb * e * e) * (s_zkbase[lane] + hk0);
      }
      float hk_n = (lane < K) ? hkB_in[(bN + jbg + 1) * K + lane] : 0.f;
      float e1_n = e1B_in[(bN + jbg + 1) * F + lane];
      for (int jj = 0; jj < 16; ++jj) {
        int jl = jbl + jj;
        int cur = jj & 1;
        if (jj < 15) {  // produce zk(jj+1) into the other buffer (hides LDS rt-latency)
          if (lane < K) {
            float dn1 = s_dxn[jl + 1].w;
            float e = __expf(-dn1) - rbm;
            s_zk[w][cur ^ 1][lane] = __expf(-rbb * e * e) * (s_zkbase[lane] + hk_n);
          }
        }
        float e1v = e1_c;
        if (jj < 14) {  // prefetch jj+2 globals
          hk_n = (lane < K) ? hkB_in[(bN + jbg + jj + 2) * K + lane] : 0.f;
          e1_c = e1_n;
          e1_n = e1B_in[(bN + jbg + jj + 2) * F + lane];
        } else {
          e1_c = e1_n;
        }
        float dn = s_dxn[jl].w;
        v2f pa = mk2(0.f, 0.f), pb = mk2(0.f, 0.f);
        const float4* z4 = (const float4*)(&s_zk[w][cur][0]);
        #pragma unroll
        for (int k4 = 0; k4 < 13; ++k4) {
          float4 z = z4[k4];
          pa += mk2(z.x, z.y) * wk2[2 * k4];
          pb += mk2(z.z, z.w) * wk2[2 * k4 + 1];
        }
        float base_ = e1b_lane + e1v + dn * w1d;
        float sum = base_ + ((pa.x + pb.x) + (pa.y + pb.y));
        t1buf[jl * 68 + lane] = silu_f(sum);
      }
    }
    // same-wave rows -> no barrier needed
    {  // sub-pass B: he = t1 @ eo2 (only er2 live), packed FMAs, b128 writes into he_T
      v2f er2[32];
      #pragma unroll
      for (int r = 0; r < 32; ++r)
        er2[r] = mk2(eo2w[(2 * r) * F + lane], eo2w[(2 * r + 1) * F + lane]);
      float b2 = eo2b[lane];
      for (int jj4 = 0; jj4 < 4; ++jj4) {
        float hv[4];
        #pragma unroll
        for (int q = 0; q < 4; ++q) {
          const float4* t4 = (const float4*)(&t1buf[(jbl + jj4 * 4 + q) * 68]);
          v2f pa = mk2(0.f, 0.f), pb = mk2(0.f, 0.f);
          #pragma unroll
          for (int r4 = 0; r4 < 16; ++r4) {
            float4 tt = t4[r4];
            pa += mk2(tt.x, tt.y) * er2[2 * r4];
            pb += mk2(tt.z, tt.w) * er2[2 * r4 + 1];
          }
          hv[q] = b2 + ((pa.x + pb.x) + (pa.y + pb.y));
        }
        *(float4*)(&s_heT[lane * 68 + jbl + jj4 * 4]) = make_float4(hv[0], hv[1], hv[2], hv[3]);
      }
    }
  }
  __syncthreads();  // he_T complete; t1buf dead -> union becomes cpart/att

  // ---- coeff partial: register-tiled 8j x 4c, 2 passes; packed FMAs (v_pk_fma_f32) ----
  {
    int c0 = 4 * (t & 63);
    v2f aX = mk2(0.f, 0.f), aXh = mk2(0.f, 0.f);
    v2f aY = mk2(0.f, 0.f), aYh = mk2(0.f, 0.f);
    v2f aZ = mk2(0.f, 0.f), aZh = mk2(0.f, 0.f);
    #pragma unroll 1
    for (int p = 0; p < 2; ++p) {
      int j0 = w * 16 + p * 8;   // local j
      v2f caccL[8], caccH[8];
      #pragma unroll
      for (int jj = 0; jj < 8; ++jj) { caccL[jj] = mk2(0.f, 0.f); caccH[jj] = mk2(0.f, 0.f); }
      for (int r = 0; r < 64; ++r) {
        float4 xm4 = *(const float4*)(&xmix[r * C + c0]);
        v2f xmL = mk2(xm4.x, xm4.y), xmH = mk2(xm4.z, xm4.w);
        const float4* hb = (const float4*)(&s_heT[r * 68 + j0]);
        float4 h0v = hb[0], h1v = hb[1];
#define CSTEP(idx, hval) \
        caccL[idx] += xmL * (hval); caccH[idx] += xmH * (hval);
        CSTEP(0, h0v.x)  CSTEP(1, h0v.y)  CSTEP(2, h0v.z)  CSTEP(3, h0v.w)
        CSTEP(4, h1v.x)  CSTEP(5, h1v.y)  CSTEP(6, h1v.z)  CSTEP(7, h1v.w)
#undef CSTEP
      }
      #pragma unroll
      for (int jj = 0; jj < 8; ++jj) {
        int jl = j0 + jj;
        float4 dq = s_dxn[jl];
        float inv = s_inv[jl];
        float s0 = tanh_f(caccL[jj].x) * inv;
        float s1 = tanh_f(caccL[jj].y) * inv;
        float s2 = tanh_f(caccH[jj].x) * inv;
        float s3 = tanh_f(caccH[jj].y) * inv;
        v2f s01 = mk2(s0, s1), s23 = mk2(s2, s3);
        aX  += s01 * dq.x; aXh += s23 * dq.x;
        aY  += s01 * dq.y; aYh += s23 * dq.y;
        aZ  += s01 * dq.z; aZh += s23 * dq.z;
      }
    }
    int cb = w * 768 + c0 * 3;
    s_cpart[cb + 0] = aX.x;  s_cpart[cb + 1]  = aY.x;  s_cpart[cb + 2]  = aZ.x;
    s_cpart[cb + 3] = aX.y;  s_cpart[cb + 4]  = aY.y;  s_cpart[cb + 5]  = aZ.y;
    s_cpart[cb + 6] = aXh.x; s_cpart[cb + 7]  = aYh.x; s_cpart[cb + 8]  = aZh.x;
    s_cpart[cb + 9] = aXh.y; s_cpart[cb + 10] = aYh.y; s_cpart[cb + 11] = aZh.y;
  }
  __syncthreads();

  // ---- combine the 4 wave partials of comb -> global ----
  {
    int c = t;
    float q0 = s_cpart[c * 3 + 0] + s_cpart[768 + c * 3 + 0] + s_cpart[1536 + c * 3 + 0] + s_cpart[2304 + c * 3 + 0];
    float q1 = s_cpart[c * 3 + 1] + s_cpart[768 + c * 3 + 1] + s_cpart[1536 + c * 3 + 1] + s_cpart[2304 + c * 3 + 1];
    float q2 = s_cpart[c * 3 + 2] + s_cpart[768 + c * 3 + 2] + s_cpart[1536 + c * 3 + 2] + s_cpart[2304 + c * 3 + 2];
    combpart[bi2 * 768 + c * 3 + 0] = q0;
    combpart[bi2 * 768 + c * 3 + 1] = q1;
    combpart[bi2 * 768 + c * 3 + 2] = q2;
  }

  // ---- logits: thread t -> (j_local = t&63, head = t>>6 = w); packed column reads ----
  {
    int jl = t & 63, hh = w;
    int jg = jh * 64 + jl;
    v2f lacc = mk2(0.f, 0.f);
    #pragma unroll 8
    for (int r = 0; r < 64; r += 2) {
      float hv0 = s_heT[r * 68 + jl];
      float hv1 = s_heT[(r + 1) * 68 + jl];
      lacc += mk2(hv0, hv1) * mk2(semw[r * H + hh], semw[(r + 1) * H + hh]);
    }
    float lg = semb[hh] + lacc.x + lacc.y;
    lg = lg > 0.f ? lg : 2.0f * (__expf(0.5f * lg) - 1.0f);  // celu alpha=2
    if (jg == i) lg -= 1e5f;
    float m = lg;
    #pragma unroll
    for (int off = 32; off > 0; off >>= 1) m = fmaxf(m, __shfl_xor(m, off));
    float e = __expf(lg - m);
    float S = e;
    #pragma unroll
    for (int off = 32; off > 0; off >>= 1) S += __shfl_xor(S, off);
    s_att[hh * 64 + jl] = e;
    if (lane == 0) { mS[bi2 * 8 + hh * 2] = m; mS[bi2 * 8 + hh * 2 + 1] = S; }
  }
  __syncthreads();

  // ---- U partial: thread t -> (f = t>>2, head = t&3); packed j-contiguous reads ----
  {
    int f = t >> 2, hh = t & 3;
    const float4* hr = (const float4*)(&s_heT[f * 68]);
    const float4* ar = (const float4*)(&s_att[hh * 64]);
    v2f pa = mk2(0.f, 0.f), pb = mk2(0.f, 0.f);
    #pragma unroll 8
    for (int jg4 = 0; jg4 < 16; ++jg4) {
      float4 hv = hr[jg4];
      float4 av = ar[jg4];
      pa += mk2(hv.x, hv.y) * mk2(av.x, av.y);
      pb += mk2(hv.z, hv.w) * mk2(av.z, av.w);
    }
    Upart[bi2 * 256 + t] = (pa.x + pb.x) + (pa.y + pb.y);
  }
}

// Light combine kernel: one block per (b,i). Rescale-combine softmax halves,
// hcin, node MLPs + residual, plus PRE (next-step precomp) or TAIL outputs.
template<int PRE, int TAIL>
__global__ __launch_bounds__(256, 2) void k_comb(
    float* __restrict__ hw,
    const float* __restrict__ mS, const float* __restrict__ Upart, const float* __restrict__ combpart,
    const float* __restrict__ p1w, const float* __restrict__ p1b,
    const float* __restrict__ p2w, const float* __restrict__ p2b,
    const float* __restrict__ n1w, const float* __restrict__ n1b,
    const float* __restrict__ n2w, const float* __restrict__ n2b,
    const float* __restrict__ ein_w, const float* __restrict__ eo1w,
    float* __restrict__ hkA_out, float* __restrict__ hkB_out,
    float* __restrict__ e1A_out, float* __restrict__ e1B_out,
    const float* __restrict__ c1w, const float* __restrict__ v1w, const float* __restrict__ v1b,
    const float* __restrict__ v2w,
    float* __restrict__ uA, float* __restrict__ uB, float* __restrict__ mbuf) {
  int blk = blockIdx.x, b = blk >> 7, i = blk & 127;
  int t = threadIdx.x, w = t >> 6, lane = t & 63;
  int bN = b * N;
  int bi2 = (bN + i) << 1;
  constexpr float invN = 1.0f / (float)N;

  __shared__ float s_hcin[C];
  __shared__ float s_cat[384];
  __shared__ float s_part[4][F];
  __shared__ float s_vec[F];
  __shared__ float s_hnew[F];

  float hi_val = (t < F) ? hw[(bN + i) * F + t] : 0.f;

  // ---- h_e combine (flash-style rescale) ----
  {
    int hh = t & 3;
    float m0 = mS[bi2 * 8 + hh * 2],       S0 = mS[bi2 * 8 + hh * 2 + 1];
    float m1 = mS[(bi2 + 1) * 8 + hh * 2], S1 = mS[(bi2 + 1) * 8 + hh * 2 + 1];
    float m = fmaxf(m0, m1);
    float w0 = __expf(m0 - m), w1 = __expf(m1 - m);
    float u = w0 * Upart[bi2 * 256 + t] + w1 * Upart[(bi2 + 1) * 256 + t];
    s_cat[64 + t] = u / (w0 * S0 + w1 * S1);
  }
  // ---- hcin combine ----
  {
    int c = t;
    float q0 = (combpart[bi2 * 768 + c * 3 + 0] + combpart[(bi2 + 1) * 768 + c * 3 + 0]) * invN;
    float q1 = (combpart[bi2 * 768 + c * 3 + 1] + combpart[(bi2 + 1) * 768 + c * 3 + 1]) * invN;
    float q2 = (combpart[bi2 * 768 + c * 3 + 2] + combpart[(bi2 + 1) * 768 + c * 3 + 2]) * invN;
    s_hcin[c] = q0 * q0 + q1 * q1 + q2 * q2;
  }
  __syncthreads();

  // ---- node phase (proven 256-thread version) ----
  {
    int c0 = w * 64;
    float a0 = 0.f, a1 = 0.f, a2 = 0.f, a3 = 0.f;
    #pragma unroll 8
    for (int cc = 0; cc < 64; cc += 4) {
      a0 += s_hcin[c0 + cc] * p1w[(c0 + cc) * F + lane];
      a1 += s_hcin[c0 + cc + 1] * p1w[(c0 + cc + 1) * F + lane];
      a2 += s_hcin[c0 + cc + 2] * p1w[(c0 + cc + 2) * F + lane];
      a3 += s_hcin[c0 + cc + 3] * p1w[(c0 + cc + 3) * F + lane];
    }
    s_part[w][lane] = (a0 + a1) + (a2 + a3);
  }
  __syncthreads();
  if (t < F) s_vec[t] = silu_f(s_part[0][t] + s_part[1][t] + s_part[2][t] + s_part[3][t] + p1b[t]);
  __syncthreads();
  if (t < F) {
    float a0 = p2b[t], a1 = 0.f, a2 = 0.f, a3 = 0.f;
    #pragma unroll 8
    for (int r = 0; r < F; r += 4) {
      a0 += s_vec[r] * p2w[r * F + t];
      a1 += s_vec[r + 1] * p2w[(r + 1) * F + t];
      a2 += s_vec[r + 2] * p2w[(r + 2) * F + t];
      a3 += s_vec[r + 3] * p2w[(r + 3) * F + t];
    }
    s_cat[t] = hi_val;
    s_cat[320 + t] = silu_f((a0 + a1) + (a2 + a3));
  }
  __syncthreads();
  {
    int r0 = w * 96;
    float a0 = 0.f, a1 = 0.f, a2 = 0.f, a3 = 0.f;
    #pragma unroll 8
    for (int rr = 0; rr < 96; rr += 4) {
      a0 += s_cat[r0 + rr] * n1w[(r0 + rr) * F + lane];
      a1 += s_cat[r0 + rr + 1] * n1w[(r0 + rr + 1) * F + lane];
      a2 += s_cat[r0 + rr + 2] * n1w[(r0 + rr + 2) * F + lane];
      a3 += s_cat[r0 + rr + 3] * n1w[(r0 + rr + 3) * F + lane];
    }
    s_part[w][lane] = (a0 + a1) + (a2 + a3);
  }
  __syncthreads();
  if (t < F) s_vec[t] = silu_f(s_part[0][t] + s_part[1][t] + s_part[2][t] + s_part[3][t] + n1b[t]);
  __syncthreads();
  if (t < F) {
    float a0 = n2b[t], a1 = 0.f, a2 = 0.f, a3 = 0.f;
    #pragma unroll 8
    for (int r = 0; r < F; r += 4) {
      a0 += s_vec[r] * n2w[r * F + t];
      a1 += s_vec[r + 1] * n2w[(r + 1) * F + t];
      a2 += s_vec[r + 2] * n2w[(r + 2) * F + t];
      a3 += s_vec[r + 3] * n2w[(r + 3) * F + t];
    }
    float hn = hi_val + silu_f((a0 + a1) + (a2 + a3));
    s_hnew[t] = hn;
    hw[(bN + i) * F + t] = hn;
  }
  __syncthreads();

  if (PRE) {  // next-step node precomp from updated h
    if (t < 228) {
      float a0 = 0.f, a1 = 0.f, a2 = 0.f, a3 = 0.f;
      if (t < 50) { int k = t;
        #pragma unroll
        for (int r = 0; r < F; r += 4) {
          a0 += s_hnew[r] * ein_w[r * K + k];       a1 += s_hnew[r + 1] * ein_w[(r + 1) * K + k];
          a2 += s_hnew[r + 2] * ein_w[(r + 2) * K + k]; a3 += s_hnew[r + 3] * ein_w[(r + 3) * K + k];
        }
        hkA_out[(bN + i) * K + k] = (a0 + a1) + (a2 + a3);
      } else if (t < 100) { int k = t - 50;
        #pragma unroll
        for (int r = 0; r < F; r += 4) {
          a0 += s_hnew[r] * ein_w[(F + r) * K + k];       a1 += s_hnew[r + 1] * ein_w[(F + r + 1) * K + k];
          a2 += s_hnew[r + 2] * ein_w[(F + r + 2) * K + k]; a3 += s_hnew[r + 3] * ein_w[(F + r + 3) * K + k];
        }
        hkB_out[(bN + i) * K + k] = (a0 + a1) + (a2 + a3);
      } else if (t < 164) { int c = t - 100;
        #pragma unroll
        for (int r = 0; r < F; r += 4) {
          a0 += s_hnew[r] * eo1w[r * F + c];       a1 += s_hnew[r + 1] * eo1w[(r + 1) * F + c];
          a2 += s_hnew[r + 2] * eo1w[(r + 2) * F + c]; a3 += s_hnew[r + 3] * eo1w[(r + 3) * F + c];
        }
        e1A_out[(bN + i) * F + c] = (a0 + a1) + (a2 + a3);
      } else { int c = t - 164;
        #pragma unroll
        for (int r = 0; r < F; r += 4) {
          a0 += s_hnew[r] * eo1w[(F + r) * F + c];       a1 += s_hnew[r + 1] * eo1w[(F + r + 1) * F + c];
          a2 += s_hnew[r + 2] * eo1w[(F + r + 2) * F + c]; a3 += s_hnew[r + 3] * eo1w[(F + r + 3) * F + c];
        }
        e1B_out[(bN + i) * F + c] = (a0 + a1) + (a2 + a3);
      }
    }
  }
  if (TAIL) {  // coord1 halves + vel scalar m for the flow tail
    if (w == 0) {
      float a0 = 0.f, a1 = 0.f, a2 = 0.f, a3 = 0.f;
      #pragma unroll
      for (int r = 0; r < F; r += 4) {
        a0 += s_hnew[r] * c1w[r * F + lane];       a1 += s_hnew[r + 1] * c1w[(r + 1) * F + lane];
        a2 += s_hnew[r + 2] * c1w[(r + 2) * F + lane]; a3 += s_hnew[r + 3] * c1w[(r + 3) * F + lane];
      }
      uA[(bN + i) * F + lane] = (a0 + a1) + (a2 + a3);
    } else if (w == 1) {
      float a0 = 0.f, a1 = 0.f, a2 = 0.f, a3 = 0.f;
      #pragma unroll
      for (int r = 0; r < F; r += 4) {
        a0 += s_hnew[r] * c1w[(F + r) * F + lane];       a1 += s_hnew[r + 1] * c1w[(F + r + 1) * F + lane];
        a2 += s_hnew[r + 2] * c1w[(F + r + 2) * F + lane]; a3 += s_hnew[r + 3] * c1w[(F + r + 3) * F + lane];
      }
      uB[(bN + i) * F + lane] = (a0 + a1) + (a2 + a3);
    } else if (w == 2) {
      float a0 = v1b[lane], a1 = 0.f, a2 = 0.f, a3 = 0.f;
      #pragma unroll
      for (int r = 0; r < F; r += 4) {
        a0 += s_hnew[r] * v1w[r * F + lane];       a1 += s_hnew[r + 1] * v1w[(r + 1) * F + lane];
        a2 += s_hnew[r + 2] * v1w[(r + 2) * F + lane]; a3 += s_hnew[r + 3] * v1w[(r + 3) * F + lane];
      }
      float tv = silu_f((a0 + a1) + (a2 + a3)) * v2w[lane];
      #pragma unroll
      for (int off = 32; off > 0; off >>= 1) tv += __shfl_down(tv, off);
      if (lane == 0) mbuf[bN + i] = tv;
    }
  }
}

// delta_v[b,i] = (1/N) sum_j (coord2 . silu(uA_i + uB_j + b)) * (x_i - x_j)
__global__ __launch_bounds__(256) void k_tail(const float* __restrict__ xb,
    const float* __restrict__ uA, const float* __restrict__ uB,
    const float* __restrict__ c1b, const float* __restrict__ c2w,
    float* __restrict__ dv) {
  int blk = blockIdx.x, b = blk >> 7, i = blk & 127;
  int t = threadIdx.x, w = t >> 6, lane = t & 63;
  __shared__ float s_xpos[N * 3];
  __shared__ float s_uAi[F];
  __shared__ float s_acc[4][3];
  for (int idx = t; idx < N * 3; idx += 256) s_xpos[idx] = xb[b * N * 3 + idx];
  if (t < F) s_uAi[t] = uA[(b * N + i) * F + t];
  __syncthreads();
  float xi0 = s_xpos[i * 3 + 0], xi1 = s_xpos[i * 3 + 1], xi2 = s_xpos[i * 3 + 2];
  float base = s_uAi[lane] + c1b[lane];
  float c2v = c2w[lane];
  float a0 = 0.f, a1 = 0.f, a2 = 0.f;
  for (int jj = 0; jj < 32; ++jj) {
    int j = w + 4 * jj;
    float tv = silu_f(base + uB[(b * N + j) * F + lane]) * c2v;
    #pragma unroll
    for (int off = 32; off > 0; off >>= 1) tv += __shfl_down(tv, off);
    if (lane == 0) {
      float dx0 = xi0 - s_xpos[j * 3 + 0];
      float dx1 = xi1 - s_xpos[j * 3 + 1];
      float dx2 = xi2 - s_xpos[j * 3 + 2];
      a0 += tv * dx0; a1 += tv * dx1; a2 += tv * dx2;
    }
  }
  if (lane == 0) { s_acc[w][0] = a0; s_acc[w][1] = a1; s_acc[w][2] = a2; }
  __syncthreads();
  if (t < 3) {
    float s = s_acc[0][t] + s_acc[1][t] + s_acc[2][t] + s_acc[3][t];
    dv[(b * N + i) * 3 + t] = s * (1.0f / (float)N);
  }
}

// apply v' = exp(m)*v + dv, x' = x + v'; center x and v; sld += 3*sum(m). One block per batch.
__global__ __launch_bounds__(128) void k_fin(float* __restrict__ xb, float* __restrict__ vb,
    const float* __restrict__ dv, const float* __restrict__ mbuf, float* __restrict__ sld) {
  int b = blockIdx.x, t = threadIdx.x;
  __shared__ float red[N];
  float m = mbuf[b * N + t];
  float em = __expf(m);
  float vv[3], xx[3];
  #pragma unroll
  for (int d = 0; d < 3; ++d) {
    int idx = (b * N + t) * 3 + d;
    vv[d] = em * vb[idx] + dv[idx];
    xx[d] = xb[idx] + vv[d];
  }
  #pragma unroll
  for (int d = 0; d < 3; ++d) {
    red[t] = xx[d];
    __syncthreads();
    for (int s = 64; s > 0; s >>= 1) { if (t < s) red[t] += red[t + s]; __syncthreads(); }
    xx[d] -= red[0] * (1.0f / (float)N);
    __syncthreads();
    red[t] = vv[d];
    __syncthreads();
    for (int s = 64; s > 0; s >>= 1) { if (t < s) red[t] += red[t + s]; __syncthreads(); }
    vv[d] -= red[0] * (1.0f / (float)N);
    __syncthreads();
  }
  #pragma unroll
  for (int d = 0; d < 3; ++d) {
    int idx = (b * N + t) * 3 + d;
    xb[idx] = xx[d];
    vb[idx] = vv[d];
  }
  red[t] = m;
  __syncthreads();
  for (int s = 64; s > 0; s >>= 1) { if (t < s) red[t] += red[t + s]; __syncthreads(); }
  if (t == 0) sld[b] += 3.0f * red[0];
}

__global__ void k_out(const float* __restrict__ xw, const float* __restrict__ vw,
                      const float* __restrict__ sld, float* __restrict__ out) {
  int t = blockIdx.x * blockDim.x + threadIdx.x;
  if (t < B * N * 3) { out[t] = xw[t]; out[B * N * 3 + t] = vw[t]; }
  if (t < B) out[2 * B * N * 3 + t] = sld[t];
}

}  // namespace

extern "C" void kernel_launch(void* const* d_in, const int* in_sizes, int n_in,
                              void* d_out, int out_size, void* d_ws, size_t ws_size,
                              hipStream_t stream) {
  const float* in_h   = (const float*)d_in[0];
  const float* in_x   = (const float*)d_in[1];
  const float* in_v   = (const float*)d_in[2];
  const float* emb1_w = (const float*)d_in[3];
  const float* emb1_b = (const float*)d_in[4];
  const float* emb2_w = (const float*)d_in[5];
  const float* emb2_b = (const float*)d_in[6];
  const float* ein_w  = (const float*)d_in[7];
  const float* ein_b  = (const float*)d_in[8];
  const float* rbf_m  = (const float*)d_in[9];
  const float* rbf_b  = (const float*)d_in[10];
  const float* eo1w   = (const float*)d_in[11];
  const float* eo1b   = (const float*)d_in[12];
  const float* eo2w   = (const float*)d_in[13];
  const float* eo2b   = (const float*)d_in[14];
  const float* xmix   = (const float*)d_in[15];
  const float* p1w    = (const float*)d_in[16];
  const float* p1b    = (const float*)d_in[17];
  const float* p2w    = (const float*)d_in[18];
  const float* p2b    = (const float*)d_in[19];
  const float* semw   = (const float*)d_in[20];
  const float* semb   = (const float*)d_in[21];
  const float* n1w    = (const float*)d_in[22];
  const float* n1b    = (const float*)d_in[23];
  const float* n2w    = (const float*)d_in[24];
  const float* n2b    = (const float*)d_in[25];
  const float* v1w    = (const float*)d_in[26];
  const float* v1b    = (const float*)d_in[27];
  const float* v2w    = (const float*)d_in[28];
  const float* c1w    = (const float*)d_in[29];
  const float* c1b    = (const float*)d_in[30];
  const float* c2w    = (const float*)d_in[31];

  float* ws   = (float*)d_ws;
  float* h0   = ws;                 // BN*F
  float* hw   = h0 + BN * F;        // BN*F
  float* hkA0 = hw + BN * F;        // BN*K
  float* hkB0 = hkA0 + BN * K;
  float* e1A0 = hkB0 + BN * K;      // BN*F
  float* e1B0 = e1A0 + BN * F;
  float* hkA1 = e1B0 + BN * F;
  float* hkB1 = hkA1 + BN * K;
  float* e1A1 = hkB1 + BN * K;
  float* e1B1 = e1A1 + BN * F;
  float* uA   = e1B1 + BN * F;      // BN*F
  float* uB   = uA + BN * F;
  float* xw   = uB + BN * F;        // BN*3
  float* vw   = xw + BN * 3;
  float* dvb  = vw + BN * 3;
  float* mbuf = dvb + BN * 3;       // BN
  float* sld  = mbuf + BN;          // B
  float* mS   = sld + B;            // BN*2*8
  float* Up   = mS + BN * 2 * 8;    // BN*2*256
  float* cp   = Up + BN * 2 * 256;  // BN*2*768

  k_init<<<6, 256, 0, stream>>>(in_x, in_v, xw, vw, sld);
  k_embed<<<BN, F, 0, stream>>>(in_h, emb1_w, emb1_b, emb2_w, emb2_b, h0);

  float* hkA[2] = {hkA0, hkA1};
  float* hkB[2] = {hkB0, hkB1};
  float* e1A[2] = {e1A0, e1A1};
  float* e1B[2] = {e1B0, e1B1};

  for (int dep = 0; dep < 2; ++dep) {
    for (int half = 0; half < 2; ++half) {
      int l = 2 * dep + half;
      float* xb = half ? vw : xw;
      float* vb = half ? xw : vw;
      const float* einw_l = ein_w + l * 2 * F * K;
      const float* einb_l = ein_b + l * K;
      const float* rbm_l  = rbf_m + l * K;
      const float* rbb_l  = rbf_b + l * K;
      const float* eo1w_l = eo1w + l * 179 * F;
      const float* eo1b_l = eo1b + l * F;
      const float* eo2w_l = eo2w + l * F * F;
      const float* eo2b_l = eo2b + l * F;
      const float* xmix_l = xmix + l * F * C;
      const float* p1w_l  = p1w + l * C * F;
      const float* p1b_l  = p1b + l * F;
      const float* p2w_l  = p2w + l * F * F;
      const float* p2b_l  = p2b + l * F;
      const float* semw_l = semw + l * F * H;
      const float* semb_l = semb + l * H;
      const float* n1w_l  = n1w + l * 384 * F;
      const float* n1b_l  = n1b + l * F;
      const float* n2w_l  = n2w + l * F * F;
      const float* n2b_l  = n2b + l * F;
      const float* v1w_l  = v1w + l * F * F;
      const float* v1b_l  = v1b + l * F;
      const float* v2w_l  = v2w + l * F;
      const float* c1w_l  = c1w + l * 2 * F * F;
      const float* c1b_l  = c1b + l * F;
      const float* c2w_l  = c2w + l * F;

      k_pre<<<BN, 256, 0, stream>>>(h0, hw, einw_l, eo1w_l, hkA[0], hkB[0], e1A[0], e1B[0]);
      // step 0: in set0 -> out set1 ; step 1: in set1 -> out set0 ; step 2: in set0, tail
      k_edge<<<BN * 2, 256, 0, stream>>>(xb, hkA[0], hkB[0], e1A[0], e1B[0],
          einb_l, rbm_l, rbb_l, eo1w_l, eo1b_l, eo2w_l, eo2b_l, xmix_l, semw_l, semb_l,
          mS, Up, cp);
      k_comb<1, 0><<<BN, 256, 0, stream>>>(hw, mS, Up, cp,
          p1w_l, p1b_l, p2w_l, p2b_l, n1w_l, n1b_l, n2w_l, n2b_l,
          einw_l, eo1w_l, hkA[1], hkB[1], e1A[1], e1B[1],
          c1w_l, v1w_l, v1b_l, v2w_l, uA, uB, mbuf);
      k_edge<<<BN * 2, 256, 0, stream>>>(xb, hkA[1], hkB[1], e1A[1], e1B[1],
          einb_l, rbm_l, rbb_l, eo1w_l, eo1b_l, eo2w_l, eo2b_l, xmix_l, semw_l, semb_l,
          mS, Up, cp);
      k_comb<1, 0><<<BN, 256, 0, stream>>>(hw, mS, Up, cp,
          p1w_l, p1b_l, p2w_l, p2b_l, n1w_l, n1b_l, n2w_l, n2b_l,
          einw_l, eo1w_l, hkA[0], hkB[0], e1A[0], e1B[0],
          c1w_l, v1w_l, v1b_l, v2w_l, uA, uB, mbuf);
      k_edge<<<BN * 2, 256, 0, stream>>>(xb, hkA[0], hkB[0], e1A[0], e1B[0],
          einb_l, rbm_l, rbb_l, eo1w_l, eo1b_l, eo2w_l, eo2b_l, xmix_l, semw_l, semb_l,
          mS, Up, cp);
      k_comb<0, 1><<<BN, 256, 0, stream>>>(hw, mS, Up, cp,
          p1w_l, p1b_l, p2w_l, p2b_l, n1w_l, n1b_l, n2w_l, n2b_l,
          einw_l, eo1w_l, hkA[1], hkB[1], e1A[1], e1B[1],
          c1w_l, v1w_l, v1b_l, v2w_l, uA, uB, mbuf);
      k_tail<<<BN, 256, 0, stream>>>(xb, uA, uB, c1b_l, c2w_l, dvb);
      k_fin<<<B, 128, 0, stream>>>(xb, vb, dvb, mbuf, sld);
    }
  }
  k_out<<<6, 256, 0, stream>>>(xw, vw, sld, (float*)d_out);
}